// Round 18
// baseline (422.259 us; speedup 1.0000x reference)
//
#include <hip/hip_runtime.h>
#include <hip/hip_fp16.h>

#define NN 100000
#define NE 1600000
#define DIN 128
#define HD 64
#define NL 4
#define NG 64
#define NBUCK ((NN + 63) / 64)  // 1563 buckets of 64 dst nodes
#define NBENC NBUCK             // encoder blocks
#define BCAP 1536               // per-bucket edge capacity (mean 1024, +16 sigma)
#define NBIN 98                 // coarse bins of 1024 dst nodes
#define BINCAP 18000            // words per coarse bin (mean 16327, +13 sigma)
#define BINA_BLOCKS 1024
#define BT 2048                 // binB LDS tile words

typedef _Float16 v4h __attribute__((ext_vector_type(4)));
typedef float v4f __attribute__((ext_vector_type(4)));

// ---------- helpers ----------
__device__ __forceinline__ float2 unpack_h2(unsigned w) {
  __half2 hh = *reinterpret_cast<__half2*>(&w);
  return __half22float2(hh);
}
__device__ __forceinline__ unsigned pack_h2(float a, float b) {
  __half2 hh = __floats2half2_rn(a, b);
  return *reinterpret_cast<unsigned*>(&hh);
}
// swizzled byte addr in f16 LDS tile, row stride 128 B (HD=64 f16)
__device__ __forceinline__ int swz128(int row, int colb) {
  return row * 128 + (colb ^ ((row & 7) << 4));
}
// row stride 256 B (DIN=128 f16)
__device__ __forceinline__ int swz256(int row, int colb) {
  return row * 256 + (colb ^ ((row & 7) << 4));
}

// ---------- weight conversion + zero-init + cnt (binary search, race-free) --
__global__ __launch_bounds__(256) void k_wconv(
    const float* __restrict__ nodew, const float* __restrict__ w1,
    const float* __restrict__ w2, const int* __restrict__ batch,
    _Float16* __restrict__ wenc, _Float16* __restrict__ w1h,
    _Float16* __restrict__ w2h, int* __restrict__ bcur,
    int* __restrict__ acur, float* __restrict__ sums,
    float* __restrict__ cnt) {
  int i = blockIdx.x * 256 + threadIdx.x;
  if (i < HD * DIN) wenc[i] = (_Float16)nodew[i];
  if (i < NL * HD * HD) {
    w1h[i] = (_Float16)w1[i];
    w2h[i] = (_Float16)w2[i];
  }
  if (i < NBUCK * 16) bcur[i] = 0;  // padded cursors (1 line apart)
  if (i < NBIN * 16) acur[i] = 0;
  if (i < NG * HD) sums[i] = 0.f;
  if (i < NG) {  // cnt[g] via binary search on sorted batch
    int lo = 0, hi = NN;
    while (lo < hi) {
      int mid = (lo + hi) >> 1;
      if (batch[mid] < i) lo = mid + 1;
      else hi = mid;
    }
    int start = lo;
    lo = 0; hi = NN;
    while (lo < hi) {
      int mid = (lo + hi) >> 1;
      if (batch[mid] < i + 1) lo = mid + 1;
      else hi = mid;
    }
    cnt[i] = (float)(lo - start);
  }
}

// ---------- pass A: LDS-chunked coarse binning (256B coalesced flushes) ----
// word = (src<<10) | (dst & 1023), bin = dst >> 10.
__global__ __launch_bounds__(256) void k_binA(const int* __restrict__ src,
                                              const int* __restrict__ dst,
                                              int* __restrict__ acur,
                                              unsigned* __restrict__ ebufA) {
  __shared__ unsigned lbuf[NBIN][96];
  __shared__ int lcnt[NBIN];
  const int tid = threadIdx.x, lane = tid & 63, wave = tid >> 6;
  for (int b = tid; b < NBIN; b += 256) lcnt[b] = 0;
  __syncthreads();

  const int tiles = NE / 512;  // 3125 exact
  for (int t = blockIdx.x; t < tiles; t += gridDim.x) {
#pragma unroll
    for (int q = 0; q < 2; q++) {
      const int e = t * 512 + q * 256 + tid;
      const int d = dst[e], s = src[e];
      const int b = d >> 10;
      const unsigned w = ((unsigned)s << 10) | (unsigned)(d & 1023);
      int p = atomicAdd(&lcnt[b], 1);
      if (p < 96) {
        lbuf[b][p] = w;
      } else {  // statistically negligible overflow: direct global append
        int gp = atomicAdd(&acur[b * 16], 1);
        if (gp < BINCAP) ebufA[(size_t)b * BINCAP + gp] = w;
      }
    }
    __syncthreads();
    // flush full 64-word (256B) chunks; wave v owns bins v, v+4, ...
    for (int bb = wave; bb < NBIN; bb += 4) {
      int n = min(lcnt[bb], 96);
      if (n >= 64) {
        int gp = 0;
        if (lane == 0) gp = atomicAdd(&acur[bb * 16], 64);
        gp = __shfl(gp, 0, 64);
        if (gp + lane < BINCAP)
          ebufA[(size_t)bb * BINCAP + gp + lane] = lbuf[bb][lane];
        int r = n - 64;  // <= 32
        unsigned tmp = (lane < r) ? lbuf[bb][64 + lane] : 0u;
        if (lane < r) lbuf[bb][lane] = tmp;
        lcnt[bb] = r;
      }
    }
    __syncthreads();
  }
  // final flush of remainders (< 96 words per bin)
  for (int bb = wave; bb < NBIN; bb += 4) {
    int n = min(lcnt[bb], 96);
    if (n > 0) {
      int gp = 0;
      if (lane == 0) gp = atomicAdd(&acur[bb * 16], n);
      gp = __shfl(gp, 0, 64);
      if (lane < n && gp + lane < BINCAP)
        ebufA[(size_t)bb * BINCAP + gp + lane] = lbuf[bb][lane];
      if (n > 64 && 64 + lane < n && gp + 64 + lane < BINCAP)
        ebufA[(size_t)bb * BINCAP + gp + 64 + lane] = lbuf[bb][64 + lane];
    }
  }
}

#define ACC4(U)                          \
  {                                      \
    float2 f0 = unpack_h2((U).x);        \
    float2 f1 = unpack_h2((U).y);        \
    acc.x += f0.x;                       \
    acc.y += f0.y;                       \
    acc.z += f1.x;                       \
    acc.w += f1.y;                       \
  }

// ---------- fused dispatch: binB (blocks 0..NBIN-1) | encoder (rest) -------
__global__ __launch_bounds__(256) void k_binB_enc(
    const int* __restrict__ acur, const unsigned* __restrict__ ebufA,
    int* __restrict__ bcur, unsigned* __restrict__ ebuf,
    const float* __restrict__ x, const _Float16* __restrict__ wenc,
    const float* __restrict__ bias, const float* __restrict__ lng,
    const float* __restrict__ lnb, unsigned* __restrict__ hp,
    unsigned* __restrict__ hn2) {
  __shared__ __align__(16) unsigned char smem[17152];
  const int tid = threadIdx.x, lane = tid & 63, wave = tid >> 6;

  if (blockIdx.x < NBIN) {
    // ----- binB: LDS tile-sort coarse bin -> final buckets (coalesced) -----
    unsigned* raw = (unsigned*)smem;               // 8192 B
    unsigned* srt = (unsigned*)(smem + 8192);      // 8192 B
    int* hist = (int*)(smem + 16384);
    int* hoff = (int*)(smem + 16448);
    int* hcur = (int*)(smem + 16512);
    int* gbase = (int*)(smem + 16576);
    const int b = blockIdx.x;
    const int n = min(acur[b * 16], BINCAP);

    for (int t0 = 0; t0 < n; t0 += BT) {
      const int tn = min(BT, n - t0);
      if (tid < 16) hist[tid] = 0;
      __syncthreads();
      for (int j = tid; j < tn; j += 256) {
        unsigned w = ebufA[(size_t)b * BINCAP + t0 + j];
        raw[j] = w;
        atomicAdd(&hist[(w >> 6) & 15], 1);  // bucket-local = dst bits 6..9
      }
      __syncthreads();
      if (tid == 0) {
        int run = 0;
#pragma unroll
        for (int q = 0; q < 16; q++) {
          hoff[q] = run;
          hcur[q] = run;
          run += hist[q];
        }
      }
      __syncthreads();
      if (tid < 16)
        gbase[tid] = atomicAdd(&bcur[(b * 16 + tid) * 16], hist[tid]);
      __syncthreads();
      for (int j = tid; j < tn; j += 256) {
        unsigned w = raw[j];
        int p = atomicAdd(&hcur[(w >> 6) & 15], 1);
        srt[p] = w;
      }
      __syncthreads();
      for (int q = wave; q < 16; q += 4) {
        const int cntq = hist[q], bs = hoff[q], gb = gbase[q];
        const size_t base = (size_t)(b * 16 + q) * BCAP;
        for (int j = lane; j < cntq; j += 64) {
          int p = gb + j;
          unsigned w = srt[bs + j];
          if (p < BCAP) ebuf[base + p] = ((w >> 10) << 6) | (w & 63u);
        }
      }
      __syncthreads();
    }
    return;
  }

  // ----- encoder: h(f16) = x @ W^T + b ; hn2 = f16(relu(LN_0(h))) -----
  unsigned char* xsb = smem;                       // 16384 B
  float* bias_s = (float*)(smem + 16384);          // 256 B
  float2* lns = (float2*)(smem + 16640);           // 512 B
  const int rl = lane & 15, kl = lane >> 4;
  const int nbase = (blockIdx.x - NBIN) * 64;

  if (tid < 64) {
    bias_s[tid] = bias[tid];
    lns[tid] = make_float2(lng[tid], lnb[tid]);
  }
  __syncthreads();

  // stage x rows: float4/lane, 2 rows per iteration, fully unrolled ->
  // 8 independent 1KB loads in flight per wave. Same LDS byte layout as
  // the float2 version (element k at byte 2k, swizzled).
#pragma unroll
  for (int g = 0; g < 8; g++) {
    const int rr = wave * 16 + g * 2 + (lane >> 5);
    const int node = nbase + rr;
    float4 xv = make_float4(0.f, 0.f, 0.f, 0.f);
    if (node < NN)
      xv = *(const float4*)(x + (size_t)node * DIN + (lane & 31) * 4);
    uint2 st;
    st.x = pack_h2(xv.x, xv.y);
    st.y = pack_h2(xv.z, xv.w);
    *(uint2*)(xsb + swz256(rr, 8 * (lane & 31))) = st;
  }
  // wave-local rows -> no barrier

  const int zrow = wave * 16 + rl;
  v4f c0 = {0.f, 0.f, 0.f, 0.f}, c1 = c0, c2 = c0, c3 = c0;
#pragma unroll
  for (int ks = 0; ks < DIN / 16; ks++) {
    uint2 braw = *(const uint2*)(xsb + swz256(zrow, ks * 32 + 8 * kl));
    v4h b = __builtin_bit_cast(v4h, braw);
    const _Float16* wk = wenc + ks * 16 + 4 * kl;
    v4h a0 = *(const v4h*)(wk + (0 * 16 + rl) * DIN);
    v4h a1 = *(const v4h*)(wk + (1 * 16 + rl) * DIN);
    v4h a2 = *(const v4h*)(wk + (2 * 16 + rl) * DIN);
    v4h a3 = *(const v4h*)(wk + (3 * 16 + rl) * DIN);
    c0 = __builtin_amdgcn_mfma_f32_16x16x16f16(a0, b, c0, 0, 0, 0);
    c1 = __builtin_amdgcn_mfma_f32_16x16x16f16(a1, b, c1, 0, 0, 0);
    c2 = __builtin_amdgcn_mfma_f32_16x16x16f16(a2, b, c2, 0, 0, 0);
    c3 = __builtin_amdgcn_mfma_f32_16x16x16f16(a3, b, c3, 0, 0, 0);
  }

  const int node = nbase + zrow;
  const bool val = node < NN;
  float vv[4][4];
  float s1 = 0.f, s2 = 0.f;
#pragma unroll
  for (int m = 0; m < 4; m++) {
    v4f am = (m == 0) ? c0 : (m == 1) ? c1 : (m == 2) ? c2 : c3;
#pragma unroll
    for (int r = 0; r < 4; r++) {
      int f = m * 16 + kl * 4 + r;
      float v = am[r] + bias_s[f];
      vv[m][r] = v;
      s1 += v;
      s2 += v * v;
    }
    if (val) {
      uint2 st;
      st.x = pack_h2(vv[m][0], vv[m][1]);
      st.y = pack_h2(vv[m][2], vv[m][3]);
      *(uint2*)(hp + (size_t)node * 32 + m * 8 + kl * 2) = st;
    }
  }
  s1 += __shfl_xor(s1, 16, 64);
  s1 += __shfl_xor(s1, 32, 64);
  s2 += __shfl_xor(s2, 16, 64);
  s2 += __shfl_xor(s2, 32, 64);
  const float mu = s1 * (1.f / 64.f);
  const float inv = rsqrtf(s2 * (1.f / 64.f) - mu * mu + 1e-5f);
  if (val) {
#pragma unroll
    for (int m = 0; m < 4; m++) {
#pragma unroll
      for (int p = 0; p < 2; p++) {
        int f0 = m * 16 + kl * 4 + 2 * p;
        float2 l0 = lns[f0], l1 = lns[f0 + 1];
        float y0 = fmaxf((vv[m][2 * p] - mu) * inv * l0.x + l0.y, 0.f);
        float y1 = fmaxf((vv[m][2 * p + 1] - mu) * inv * l1.x + l1.y, 0.f);
        hn2[(size_t)node * 32 + m * 8 + kl * 2 + p] = pack_h2(y0, y1);
      }
    }
  }
}

// shared macro: LDS counting-sort of this block's bucket into elds/off
#define BUCKET_SORT()                                                       \
  {                                                                         \
    const int n = min(bcur[blockIdx.x * 16], BCAP);                         \
    unsigned ew[6];                                                         \
    _Pragma("unroll") for (int q = 0; q < 6; q++) {                         \
      int j = tid + q * 256;                                                \
      ew[q] = (j < n) ? ebuf[(size_t)blockIdx.x * BCAP + j] : 0xFFFFFFFFu;  \
    }                                                                       \
    __syncthreads();                                                        \
    _Pragma("unroll") for (int q = 0; q < 6; q++) if (ew[q] != 0xFFFFFFFFu) \
        atomicAdd(&cur2[ew[q] & 63], 1);                                    \
    __syncthreads();                                                        \
    if (wave == 0) {                                                        \
      int v = cur2[lane];                                                   \
      int inc = v;                                                          \
      _Pragma("unroll") for (int d = 1; d < 64; d <<= 1) {                  \
        int t = __shfl_up(inc, d, 64);                                      \
        if (lane >= d) inc += t;                                            \
      }                                                                     \
      off[lane + 1] = inc;                                                  \
      if (lane == 0) off[0] = 0;                                            \
      cur2[lane] = inc - v;                                                 \
    }                                                                       \
    __syncthreads();                                                        \
    _Pragma("unroll") for (int q = 0; q < 6; q++) if (ew[q] != 0xFFFFFFFFu) \
        {                                                                   \
      int d = ew[q] & 63;                                                   \
      int p = atomicAdd(&cur2[d], 1);                                       \
      elds[p] = ew[q] >> 6;                                                 \
    }                                                                       \
    __syncthreads();                                                        \
  }

// shared macro: gather into zsb (quarter-wave owns node, batch-8)
#define GATHER()                                                            \
  _Pragma("unroll 1") for (int g = 0; g < 4; g++) {                         \
    const int nl = wave * 16 + g * 4 + qtr;                                 \
    const int node = nbase + nl;                                            \
    const bool valid = node < NN;                                           \
    int j = off[nl];                                                        \
    const int j1 = off[nl + 1];                                             \
    float4 acc = make_float4(0.f, 0.f, 0.f, 0.f);                           \
    if (valid) {                                                            \
      uint2 u = hnv[(size_t)node * 16 + ql];                                \
      float2 f0 = unpack_h2(u.x), f1 = unpack_h2(u.y);                      \
      acc.x = e * f0.x;                                                     \
      acc.y = e * f0.y;                                                     \
      acc.z = e * f1.x;                                                     \
      acc.w = e * f1.y;                                                     \
    }                                                                       \
    for (; j + 8 <= j1; j += 8) {                                           \
      int s_[8];                                                            \
      uint2 u_[8];                                                          \
      _Pragma("unroll") for (int t = 0; t < 8; t++) s_[t] = elds[j + t];    \
      _Pragma("unroll") for (int t = 0; t < 8; t++) u_[t] =                 \
          hnv[(size_t)s_[t] * 16 + ql];                                     \
      _Pragma("unroll") for (int t = 0; t < 8; t++) ACC4(u_[t])             \
    }                                                                       \
    if (j + 4 <= j1) {                                                      \
      int s_[4];                                                            \
      uint2 u_[4];                                                          \
      _Pragma("unroll") for (int t = 0; t < 4; t++) s_[t] = elds[j + t];    \
      _Pragma("unroll") for (int t = 0; t < 4; t++) u_[t] =                 \
          hnv[(size_t)s_[t] * 16 + ql];                                     \
      _Pragma("unroll") for (int t = 0; t < 4; t++) ACC4(u_[t])             \
      j += 4;                                                               \
    }                                                                       \
    for (; j < j1; j++) {                                                   \
      int s = elds[j];                                                      \
      uint2 u = hnv[(size_t)s * 16 + ql];                                   \
      ACC4(u)                                                               \
    }                                                                       \
    uint2 wv;                                                               \
    wv.x = pack_h2(acc.x, acc.y);                                           \
    wv.y = pack_h2(acc.z, acc.w);                                           \
    *(uint2*)(zsb + swz128(nl, ql * 8)) = wv;                               \
  }

// shared macro: MFMA MLP (GEMM1 + bn1/relu + GEMM2 into d0..d3)
#define MLP()                                                               \
  v4f c0 = {0.f, 0.f, 0.f, 0.f}, c1 = c0, c2 = c0, c3 = c0;                 \
  _Pragma("unroll") for (int ks = 0; ks < 4; ks++) {                        \
    uint2 braw = *(const uint2*)(zsb + swz128(zrow, ks * 32 + 8 * kl));     \
    v4h b = __builtin_bit_cast(v4h, braw);                                  \
    const _Float16* wk = w1h + ks * 16 + 4 * kl;                            \
    v4h a0 = *(const v4h*)(wk + (0 * 16 + rl) * HD);                        \
    v4h a1 = *(const v4h*)(wk + (1 * 16 + rl) * HD);                        \
    v4h a2 = *(const v4h*)(wk + (2 * 16 + rl) * HD);                        \
    v4h a3 = *(const v4h*)(wk + (3 * 16 + rl) * HD);                        \
    c0 = __builtin_amdgcn_mfma_f32_16x16x16f16(a0, b, c0, 0, 0, 0);         \
    c1 = __builtin_amdgcn_mfma_f32_16x16x16f16(a1, b, c1, 0, 0, 0);         \
    c2 = __builtin_amdgcn_mfma_f32_16x16x16f16(a2, b, c2, 0, 0, 0);         \
    c3 = __builtin_amdgcn_mfma_f32_16x16x16f16(a3, b, c3, 0, 0, 0);         \
  }                                                                         \
  _Pragma("unroll") for (int m = 0; m < 4; m++) {                           \
    v4f am = (m == 0) ? c0 : (m == 1) ? c1 : (m == 2) ? c2 : c3;            \
    float z[4];                                                             \
    _Pragma("unroll") for (int r = 0; r < 4; r++) {                         \
      int f = m * 16 + kl * 4 + r;                                          \
      float2 ac = acs1[f];                                                  \
      z[r] = fmaxf(fmaf(am[r], ac.x, ac.y), 0.f);                           \
    }                                                                       \
    *(unsigned*)(zsb + swz128(zrow, m * 32 + kl * 8)) = pack_h2(z[0], z[1]);\
    *(unsigned*)(zsb + swz128(zrow, m * 32 + kl * 8 + 4)) =                 \
        pack_h2(z[2], z[3]);                                                \
  }                                                                         \
  v4f d0 = {0.f, 0.f, 0.f, 0.f}, d1 = d0, d2 = d0, d3 = d0;                 \
  _Pragma("unroll") for (int ks = 0; ks < 4; ks++) {                        \
    uint2 braw = *(const uint2*)(zsb + swz128(zrow, ks * 32 + 8 * kl));     \
    v4h b = __builtin_bit_cast(v4h, braw);                                  \
    const _Float16* wk = w2h + ks * 16 + 4 * kl;                            \
    v4h a0 = *(const v4h*)(wk + (0 * 16 + rl) * HD);                        \
    v4h a1 = *(const v4h*)(wk + (1 * 16 + rl) * HD);                        \
    v4h a2 = *(const v4h*)(wk + (2 * 16 + rl) * HD);                        \
    v4h a3 = *(const v4h*)(wk + (3 * 16 + rl) * HD);                        \
    d0 = __builtin_amdgcn_mfma_f32_16x16x16f16(a0, b, d0, 0, 0, 0);         \
    d1 = __builtin_amdgcn_mfma_f32_16x16x16f16(a1, b, d1, 0, 0, 0);         \
    d2 = __builtin_amdgcn_mfma_f32_16x16x16f16(a2, b, d2, 0, 0, 0);         \
    d3 = __builtin_amdgcn_mfma_f32_16x16x16f16(a3, b, d3, 0, 0, 0);         \
  }

#define LAYER_PREAMBLE()                                                    \
  const int tid = threadIdx.x, lane = tid & 63, wave = tid >> 6;            \
  const int rl = lane & 15, kl = lane >> 4;                                 \
  const int qtr = kl, ql = rl;                                              \
  const int nbase = blockIdx.x * 64;                                        \
  const float e = 1.f + eps_arr[layer];                                     \
  const uint2* hnv = (const uint2*)hn2_in;                                  \
  if (tid < 64) {                                                           \
    float a1 = g1[tid] * rsqrtf(v1[tid] + 1e-5f);                           \
    acs1[tid] = make_float2(a1, (b1[tid] - m1[tid]) * a1 + bb1[tid]);       \
    float a2 = g2[tid] * rsqrtf(v2[tid] + 1e-5f);                           \
    acs2[tid] = make_float2(a2, (b2[tid] - m2[tid]) * a2 + bb2[tid]);       \
    cur2[tid] = 0;                                                          \
  }

// ---------- fused layer (layers 0..NL-2): LN epilogue, no atomics ----------
// hn2_in and hn2_out MUST be distinct buffers (cross-block race otherwise).
__global__ __launch_bounds__(256) void k_layer(
    const unsigned* __restrict__ hn2_in, unsigned* __restrict__ hp,
    unsigned* __restrict__ hn2_out, const int* __restrict__ bcur,
    const unsigned* __restrict__ ebuf, const float* __restrict__ eps_arr,
    int layer, const _Float16* __restrict__ w1h, const float* __restrict__ b1,
    const float* __restrict__ g1, const float* __restrict__ bb1,
    const float* __restrict__ m1, const float* __restrict__ v1,
    const _Float16* __restrict__ w2h, const float* __restrict__ b2,
    const float* __restrict__ g2, const float* __restrict__ bb2,
    const float* __restrict__ m2, const float* __restrict__ v2,
    const float* __restrict__ lng, const float* __restrict__ lnb) {
  __shared__ __align__(16) unsigned char zsb[64 * 128];
  __shared__ unsigned elds[BCAP];
  __shared__ int off[65];
  __shared__ int cur2[64];
  __shared__ float2 acs1[64], acs2[64], lns[64];
  LAYER_PREAMBLE()
  if (tid < 64) lns[tid] = make_float2(lng[tid], lnb[tid]);
  BUCKET_SORT()
  GATHER()
  const int zrow = wave * 16 + rl;
  MLP()

  // epilogue: bn2+relu, residual (f16 h), store hp, LN+relu, store hn2_out
  const int node = nbase + zrow;
  const bool val = node < NN;
  float vv[4][4];
  float s1 = 0.f, s2 = 0.f;
#pragma unroll
  for (int m = 0; m < 4; m++) {
    v4f am = (m == 0) ? d0 : (m == 1) ? d1 : (m == 2) ? d2 : d3;
    float hv[4] = {0.f, 0.f, 0.f, 0.f};
    if (val) {
      uint2 hraw = *(const uint2*)(hp + (size_t)node * 32 + m * 8 + kl * 2);
      float2 ha = unpack_h2(hraw.x), hb = unpack_h2(hraw.y);
      hv[0] = ha.x;
      hv[1] = ha.y;
      hv[2] = hb.x;
      hv[3] = hb.y;
    }
#pragma unroll
    for (int r = 0; r < 4; r++) {
      int f = m * 16 + kl * 4 + r;
      float2 ac = acs2[f];
      float z2 = fmaxf(fmaf(am[r], ac.x, ac.y), 0.f);
      float v = hv[r] + z2;
      vv[m][r] = v;
      s1 += v;
      s2 += v * v;
    }
    if (val) {
      uint2 st;
      st.x = pack_h2(vv[m][0], vv[m][1]);
      st.y = pack_h2(vv[m][2], vv[m][3]);
      *(uint2*)(hp + (size_t)node * 32 + m * 8 + kl * 2) = st;
    }
  }
  s1 += __shfl_xor(s1, 16, 64);
  s1 += __shfl_xor(s1, 32, 64);
  s2 += __shfl_xor(s2, 16, 64);
  s2 += __shfl_xor(s2, 32, 64);
  const float mu = s1 * (1.f / 64.f);
  const float inv = rsqrtf(s2 * (1.f / 64.f) - mu * mu + 1e-5f);
  if (val) {
#pragma unroll
    for (int m = 0; m < 4; m++) {
#pragma unroll
      for (int p = 0; p < 2; p++) {
        int f0 = m * 16 + kl * 4 + 2 * p;
        float2 l0 = lns[f0], l1 = lns[f0 + 1];
        float y0 = fmaxf((vv[m][2 * p] - mu) * inv * l0.x + l0.y, 0.f);
        float y1 = fmaxf((vv[m][2 * p + 1] - mu) * inv * l1.x + l1.y, 0.f);
        hn2_out[(size_t)node * 32 + m * 8 + kl * 2 + p] = pack_h2(y0, y1);
      }
    }
  }
}

// ---------- last layer: no LN, no hn2_out, no atomics; writes hp only ------
__global__ __launch_bounds__(256) void k_layer3(
    const unsigned* __restrict__ hn2_in, unsigned* __restrict__ hp,
    const int* __restrict__ bcur, const unsigned* __restrict__ ebuf,
    const float* __restrict__ eps_arr, int layer,
    const _Float16* __restrict__ w1h, const float* __restrict__ b1,
    const float* __restrict__ g1, const float* __restrict__ bb1,
    const float* __restrict__ m1, const float* __restrict__ v1,
    const _Float16* __restrict__ w2h, const float* __restrict__ b2,
    const float* __restrict__ g2, const float* __restrict__ bb2,
    const float* __restrict__ m2, const float* __restrict__ v2) {
  __shared__ __align__(16) unsigned char zsb[64 * 128];
  __shared__ unsigned elds[BCAP];
  __shared__ int off[65];
  __shared__ int cur2[64];
  __shared__ float2 acs1[64], acs2[64];
  LAYER_PREAMBLE()
  BUCKET_SORT()
  GATHER()
  const int zrow = wave * 16 + rl;
  MLP()

  const int node = nbase + zrow;
  const bool val = node < NN;
#pragma unroll
  for (int m = 0; m < 4; m++) {
    v4f am = (m == 0) ? d0 : (m == 1) ? d1 : (m == 2) ? d2 : d3;
    float hv[4] = {0.f, 0.f, 0.f, 0.f};
    if (val) {
      uint2 hraw = *(const uint2*)(hp + (size_t)node * 32 + m * 8 + kl * 2);
      float2 ha = unpack_h2(hraw.x), hb = unpack_h2(hraw.y);
      hv[0] = ha.x;
      hv[1] = ha.y;
      hv[2] = hb.x;
      hv[3] = hb.y;
    }
    float vv[4];
#pragma unroll
    for (int r = 0; r < 4; r++) {
      int f = m * 16 + kl * 4 + r;
      float2 ac = acs2[f];
      float z2 = fmaxf(fmaf(am[r], ac.x, ac.y), 0.f);
      vv[r] = hv[r] + z2;
    }
    if (val) {
      uint2 st;
      st.x = pack_h2(vv[0], vv[1]);
      st.y = pack_h2(vv[2], vv[3]);
      *(uint2*)(hp + (size_t)node * 32 + m * 8 + kl * 2) = st;
    }
  }
}

// ---------- pooling (h in f16) ----------
__global__ __launch_bounds__(256) void k_pool(const unsigned* __restrict__ hp,
                                              const int* __restrict__ batch,
                                              float* __restrict__ sums) {
  const int lane = threadIdx.x & 63;
  const int gw = blockIdx.x * 4 + (threadIdx.x >> 6);
  const int base = gw * 64;
  if (base >= NN) return;
  const int end = min(base + 64, NN);
  float acc = 0.f;
  int cur = batch[base];
  for (int n = base; n < end; n++) {
    int g = batch[n];
    if (g != cur) {
      atomicAdd(&sums[cur * HD + lane], acc);
      acc = 0.f;
      cur = g;
    }
    unsigned u = hp[(size_t)n * 32 + (lane >> 1)];
    float2 f = unpack_h2(u);
    acc += (lane & 1) ? f.y : f.x;
  }
  atomicAdd(&sums[cur * HD + lane], acc);
}

__global__ __launch_bounds__(256) void k_div(const float* __restrict__ sums,
                                             const float* __restrict__ cnt,
                                             float* __restrict__ out) {
  int i = blockIdx.x * 256 + threadIdx.x;
  if (i < NG * HD) out[i] = sums[i] / fmaxf(cnt[i >> 6], 1.f);
}

// ---------- launch ----------
extern "C" void kernel_launch(void* const* d_in, const int* in_sizes, int n_in,
                              void* d_out, int out_size, void* d_ws,
                              size_t ws_size, hipStream_t stream) {
  const float* x = (const float*)d_in[0];
  const float* node_w = (const float*)d_in[1];
  const float* node_b = (const float*)d_in[2];
  const float* ln_g = (const float*)d_in[3];
  const float* ln_b = (const float*)d_in[4];
  const float* eps = (const float*)d_in[5];
  const float* w1 = (const float*)d_in[6];
  const float* b1 = (const float*)d_in[7];
  const float* bn1_g = (const float*)d_in[8];
  const float* bn1_b = (const float*)d_in[9];
  const float* bn1_m = (const float*)d_in[10];
  const float* bn1_v = (const float*)d_in[11];
  const float* w2 = (const float*)d_in[12];
  const float* b2 = (const float*)d_in[13];
  const float* bn2_g = (const float*)d_in[14];
  const float* bn2_b = (const float*)d_in[15];
  const float* bn2_m = (const float*)d_in[16];
  const float* bn2_v = (const float*)d_in[17];
  const int* edge_index = (const int*)d_in[18];
  const int* batch = (const int*)d_in[19];
  float* out = (float*)d_out;

  char* ws = (char*)d_ws;
  size_t off = 0;
  auto carve = [&](size_t bytes) {
    void* p = ws + off;
    off += (bytes + 255) & ~(size_t)255;
    return p;
  };
  unsigned* hp = (unsigned*)carve((size_t)NN * 32 * sizeof(unsigned));
  unsigned* hn2a = (unsigned*)carve((size_t)NN * 32 * sizeof(unsigned));
  unsigned* hn2b = (unsigned*)carve((size_t)NN * 32 * sizeof(unsigned));
  unsigned* ebuf = (unsigned*)carve((size_t)NBUCK * BCAP * sizeof(unsigned));
  unsigned* ebufA = (unsigned*)carve((size_t)NBIN * BINCAP * sizeof(unsigned));
  int* bcur = (int*)carve((size_t)NBUCK * 16 * sizeof(int));
  int* acur = (int*)carve((size_t)NBIN * 16 * sizeof(int));
  float* sums = (float*)carve((size_t)NG * HD * sizeof(float));
  float* cnt = (float*)carve((size_t)NG * sizeof(float));
  _Float16* wenc = (_Float16*)carve((size_t)HD * DIN * sizeof(_Float16));
  _Float16* w1h = (_Float16*)carve((size_t)NL * HD * HD * sizeof(_Float16));
  _Float16* w2h = (_Float16*)carve((size_t)NL * HD * HD * sizeof(_Float16));

  const int* e_src = edge_index;
  const int* e_dst = edge_index + NE;

  k_wconv<<<(NBUCK * 16 + 255) / 256, 256, 0, stream>>>(
      node_w, w1, w2, batch, wenc, w1h, w2h, bcur, acur, sums, cnt);
  k_binA<<<BINA_BLOCKS, 256, 0, stream>>>(e_src, e_dst, acur, ebufA);
  k_binB_enc<<<NBIN + NBENC, 256, 0, stream>>>(acur, ebufA, bcur, ebuf, x,
                                               wenc, node_b, ln_g, ln_b, hp,
                                               hn2a);

  for (int l = 0; l < NL - 1; l++) {
    const unsigned* hin = (l & 1) ? hn2b : hn2a;
    unsigned* hout = (l & 1) ? hn2a : hn2b;
    k_layer<<<NBUCK, 256, 0, stream>>>(
        hin, hp, hout, bcur, ebuf, eps, l, w1h + (size_t)l * HD * HD,
        b1 + l * HD, bn1_g + l * HD, bn1_b + l * HD, bn1_m + l * HD,
        bn1_v + l * HD, w2h + (size_t)l * HD * HD, b2 + l * HD, bn2_g + l * HD,
        bn2_b + l * HD, bn2_m + l * HD, bn2_v + l * HD, ln_g + (l + 1) * HD,
        ln_b + (l + 1) * HD);
  }
  {
    const int l = NL - 1;
    const unsigned* hin = (l & 1) ? hn2b : hn2a;
    k_layer3<<<NBUCK, 256, 0, stream>>>(
        hin, hp, bcur, ebuf, eps, l, w1h + (size_t)l * HD * HD, b1 + l * HD,
        bn1_g + l * HD, bn1_b + l * HD, bn1_m + l * HD, bn1_v + l * HD,
        w2h + (size_t)l * HD * HD, b2 + l * HD, bn2_g + l * HD, bn2_b + l * HD,
        bn2_m + l * HD, bn2_v + l * HD);
  }

  k_pool<<<(NN + 255) / 256, 256, 0, stream>>>(hp, batch, sums);
  k_div<<<(NG * HD + 255) / 256, 256, 0, stream>>>(sums, cnt, out);
}

// Round 19
// 381.521 us; speedup vs baseline: 1.1068x; 1.1068x over previous
//
#include <hip/hip_runtime.h>
#include <hip/hip_fp16.h>

#define NN 100000
#define NE 1600000
#define DIN 128
#define HD 64
#define NL 4
#define NG 64
#define NBUCK ((NN + 63) / 64)  // 1563 buckets of 64 dst nodes
#define NBENC NBUCK             // encoder blocks
#define BCAP 1536               // per-bucket edge capacity (mean 1024, +16 sigma)
#define NBIN 98                 // coarse bins of 1024 dst nodes
#define BINCAP 18000            // words per coarse bin (mean 16327, +13 sigma)
#define BINA_BLOCKS 512
#define BT 2048                 // binB LDS tile words
#define SB 4                    // binB slices per bin (parallelize the tail)

typedef _Float16 v4h __attribute__((ext_vector_type(4)));
typedef float v4f __attribute__((ext_vector_type(4)));

// ---------- helpers ----------
__device__ __forceinline__ float2 unpack_h2(unsigned w) {
  __half2 hh = *reinterpret_cast<__half2*>(&w);
  return __half22float2(hh);
}
__device__ __forceinline__ unsigned pack_h2(float a, float b) {
  __half2 hh = __floats2half2_rn(a, b);
  return *reinterpret_cast<unsigned*>(&hh);
}
// swizzled byte addr in f16 LDS tile, row stride 128 B (HD=64 f16)
__device__ __forceinline__ int swz128(int row, int colb) {
  return row * 128 + (colb ^ ((row & 7) << 4));
}
// row stride 256 B (DIN=128 f16)
__device__ __forceinline__ int swz256(int row, int colb) {
  return row * 256 + (colb ^ ((row & 7) << 4));
}

// ---------- weight conversion + zero-init + cnt (binary search, race-free) --
__global__ __launch_bounds__(256) void k_wconv(
    const float* __restrict__ nodew, const float* __restrict__ w1,
    const float* __restrict__ w2, const int* __restrict__ batch,
    _Float16* __restrict__ wenc, _Float16* __restrict__ w1h,
    _Float16* __restrict__ w2h, int* __restrict__ bcur,
    int* __restrict__ acur, float* __restrict__ sums,
    float* __restrict__ cnt) {
  int i = blockIdx.x * 256 + threadIdx.x;
  if (i < HD * DIN) wenc[i] = (_Float16)nodew[i];
  if (i < NL * HD * HD) {
    w1h[i] = (_Float16)w1[i];
    w2h[i] = (_Float16)w2[i];
  }
  if (i < NBUCK * 16) bcur[i] = 0;  // padded cursors (1 line apart)
  if (i < NBIN * 16) acur[i] = 0;
  if (i < NG * HD) sums[i] = 0.f;
  if (i < NG) {  // cnt[g] via binary search on sorted batch
    int lo = 0, hi = NN;
    while (lo < hi) {
      int mid = (lo + hi) >> 1;
      if (batch[mid] < i) lo = mid + 1;
      else hi = mid;
    }
    int start = lo;
    lo = 0; hi = NN;
    while (lo < hi) {
      int mid = (lo + hi) >> 1;
      if (batch[mid] < i + 1) lo = mid + 1;
      else hi = mid;
    }
    cnt[i] = (float)(lo - start);
  }
}

// ---------- pass A: LDS-chunked coarse binning (256B coalesced flushes) ----
// word = (src<<10) | (dst & 1023), bin = dst >> 10.
__global__ __launch_bounds__(256) void k_binA(const int* __restrict__ src,
                                              const int* __restrict__ dst,
                                              int* __restrict__ acur,
                                              unsigned* __restrict__ ebufA) {
  __shared__ unsigned lbuf[NBIN][96];
  __shared__ int lcnt[NBIN];
  const int tid = threadIdx.x, lane = tid & 63, wave = tid >> 6;
  for (int b = tid; b < NBIN; b += 256) lcnt[b] = 0;
  __syncthreads();

  const int tiles = NE / 512;  // 3125 exact
  for (int t = blockIdx.x; t < tiles; t += gridDim.x) {
#pragma unroll
    for (int q = 0; q < 2; q++) {
      const int e = t * 512 + q * 256 + tid;
      const int d = dst[e], s = src[e];
      const int b = d >> 10;
      const unsigned w = ((unsigned)s << 10) | (unsigned)(d & 1023);
      int p = atomicAdd(&lcnt[b], 1);
      if (p < 96) {
        lbuf[b][p] = w;
      } else {  // statistically negligible overflow: direct global append
        int gp = atomicAdd(&acur[b * 16], 1);
        if (gp < BINCAP) ebufA[(size_t)b * BINCAP + gp] = w;
      }
    }
    __syncthreads();
    // flush full 64-word (256B) chunks; wave v owns bins v, v+4, ...
    for (int bb = wave; bb < NBIN; bb += 4) {
      int n = min(lcnt[bb], 96);
      if (n >= 64) {
        int gp = 0;
        if (lane == 0) gp = atomicAdd(&acur[bb * 16], 64);
        gp = __shfl(gp, 0, 64);
        if (gp + lane < BINCAP)
          ebufA[(size_t)bb * BINCAP + gp + lane] = lbuf[bb][lane];
        int r = n - 64;  // <= 32
        unsigned tmp = (lane < r) ? lbuf[bb][64 + lane] : 0u;
        if (lane < r) lbuf[bb][lane] = tmp;
        lcnt[bb] = r;
      }
    }
    __syncthreads();
  }
  // final flush of remainders (< 96 words per bin)
  for (int bb = wave; bb < NBIN; bb += 4) {
    int n = min(lcnt[bb], 96);
    if (n > 0) {
      int gp = 0;
      if (lane == 0) gp = atomicAdd(&acur[bb * 16], n);
      gp = __shfl(gp, 0, 64);
      if (lane < n && gp + lane < BINCAP)
        ebufA[(size_t)bb * BINCAP + gp + lane] = lbuf[bb][lane];
      if (n > 64 && 64 + lane < n && gp + 64 + lane < BINCAP)
        ebufA[(size_t)bb * BINCAP + gp + 64 + lane] = lbuf[bb][64 + lane];
    }
  }
}

#define ACC4(U)                          \
  {                                      \
    float2 f0 = unpack_h2((U).x);        \
    float2 f1 = unpack_h2((U).y);        \
    acc.x += f0.x;                       \
    acc.y += f0.y;                       \
    acc.z += f1.x;                       \
    acc.w += f1.y;                       \
  }

// ---------- fused dispatch: binB slices (blocks 0..NBIN*SB-1) | encoder ----
// binB sliced 4-way per bin so its per-block serial work no longer tails the
// dispatch. Per-tile bcur reservations are atomic -> slice-safe.
__global__ __launch_bounds__(256) void k_binB_enc(
    const int* __restrict__ acur, const unsigned* __restrict__ ebufA,
    int* __restrict__ bcur, unsigned* __restrict__ ebuf,
    const float* __restrict__ x, const _Float16* __restrict__ wenc,
    const float* __restrict__ bias, const float* __restrict__ lng,
    const float* __restrict__ lnb, unsigned* __restrict__ hp,
    unsigned* __restrict__ hn2) {
  __shared__ __align__(16) unsigned char smem[17152];
  const int tid = threadIdx.x, lane = tid & 63, wave = tid >> 6;

  if (blockIdx.x < NBIN * SB) {
    // ----- binB: LDS tile-sort coarse-bin slice -> final buckets -----
    unsigned* raw = (unsigned*)smem;               // 8192 B
    unsigned* srt = (unsigned*)(smem + 8192);      // 8192 B
    int* hist = (int*)(smem + 16384);
    int* hoff = (int*)(smem + 16448);
    int* hcur = (int*)(smem + 16512);
    int* gbase = (int*)(smem + 16576);
    const int b = blockIdx.x / SB, sl = blockIdx.x % SB;
    const int n = min(acur[b * 16], BINCAP);
    const int per = (n + SB - 1) / SB;
    const int j0 = sl * per, j1 = min(j0 + per, n);

    for (int t0 = j0; t0 < j1; t0 += BT) {
      const int tn = min(BT, j1 - t0);
      if (tid < 16) hist[tid] = 0;
      __syncthreads();
      for (int j = tid; j < tn; j += 256) {
        unsigned w = ebufA[(size_t)b * BINCAP + t0 + j];
        raw[j] = w;
        atomicAdd(&hist[(w >> 6) & 15], 1);  // bucket-local = dst bits 6..9
      }
      __syncthreads();
      if (tid == 0) {
        int run = 0;
#pragma unroll
        for (int q = 0; q < 16; q++) {
          hoff[q] = run;
          hcur[q] = run;
          run += hist[q];
        }
      }
      __syncthreads();
      if (tid < 16)
        gbase[tid] = atomicAdd(&bcur[(b * 16 + tid) * 16], hist[tid]);
      __syncthreads();
      for (int j = tid; j < tn; j += 256) {
        unsigned w = raw[j];
        int p = atomicAdd(&hcur[(w >> 6) & 15], 1);
        srt[p] = w;
      }
      __syncthreads();
      for (int q = wave; q < 16; q += 4) {
        const int cntq = hist[q], bs = hoff[q], gb = gbase[q];
        const size_t base = (size_t)(b * 16 + q) * BCAP;
        for (int j = lane; j < cntq; j += 64) {
          int p = gb + j;
          unsigned w = srt[bs + j];
          if (p < BCAP) ebuf[base + p] = ((w >> 10) << 6) | (w & 63u);
        }
      }
      __syncthreads();
    }
    return;
  }

  // ----- encoder: h(f16) = x @ W^T + b ; hn2 = f16(relu(LN_0(h))) -----
  unsigned char* xsb = smem;                       // 16384 B
  float* bias_s = (float*)(smem + 16384);          // 256 B
  float2* lns = (float2*)(smem + 16640);           // 512 B
  const int rl = lane & 15, kl = lane >> 4;
  const int nbase = (blockIdx.x - NBIN * SB) * 64;

  if (tid < 64) {
    bias_s[tid] = bias[tid];
    lns[tid] = make_float2(lng[tid], lnb[tid]);
  }
  __syncthreads();

#pragma unroll 1
  for (int rr16 = 0; rr16 < 16; rr16++) {
    const int rr = wave * 16 + rr16;
    const int node = nbase + rr;
    float2 xv = make_float2(0.f, 0.f);
    if (node < NN) xv = *(const float2*)(x + (size_t)node * DIN + 2 * lane);
    *(unsigned*)(xsb + swz256(rr, 4 * lane)) = pack_h2(xv.x, xv.y);
  }
  // wave-local rows -> no barrier

  const int zrow = wave * 16 + rl;
  v4f c0 = {0.f, 0.f, 0.f, 0.f}, c1 = c0, c2 = c0, c3 = c0;
#pragma unroll
  for (int ks = 0; ks < DIN / 16; ks++) {
    uint2 braw = *(const uint2*)(xsb + swz256(zrow, ks * 32 + 8 * kl));
    v4h b = __builtin_bit_cast(v4h, braw);
    const _Float16* wk = wenc + ks * 16 + 4 * kl;
    v4h a0 = *(const v4h*)(wk + (0 * 16 + rl) * DIN);
    v4h a1 = *(const v4h*)(wk + (1 * 16 + rl) * DIN);
    v4h a2 = *(const v4h*)(wk + (2 * 16 + rl) * DIN);
    v4h a3 = *(const v4h*)(wk + (3 * 16 + rl) * DIN);
    c0 = __builtin_amdgcn_mfma_f32_16x16x16f16(a0, b, c0, 0, 0, 0);
    c1 = __builtin_amdgcn_mfma_f32_16x16x16f16(a1, b, c1, 0, 0, 0);
    c2 = __builtin_amdgcn_mfma_f32_16x16x16f16(a2, b, c2, 0, 0, 0);
    c3 = __builtin_amdgcn_mfma_f32_16x16x16f16(a3, b, c3, 0, 0, 0);
  }

  const int node = nbase + zrow;
  const bool val = node < NN;
  float vv[4][4];
  float s1 = 0.f, s2 = 0.f;
#pragma unroll
  for (int m = 0; m < 4; m++) {
    v4f am = (m == 0) ? c0 : (m == 1) ? c1 : (m == 2) ? c2 : c3;
#pragma unroll
    for (int r = 0; r < 4; r++) {
      int f = m * 16 + kl * 4 + r;
      float v = am[r] + bias_s[f];
      vv[m][r] = v;
      s1 += v;
      s2 += v * v;
    }
    if (val) {
      uint2 st;
      st.x = pack_h2(vv[m][0], vv[m][1]);
      st.y = pack_h2(vv[m][2], vv[m][3]);
      *(uint2*)(hp + (size_t)node * 32 + m * 8 + kl * 2) = st;
    }
  }
  s1 += __shfl_xor(s1, 16, 64);
  s1 += __shfl_xor(s1, 32, 64);
  s2 += __shfl_xor(s2, 16, 64);
  s2 += __shfl_xor(s2, 32, 64);
  const float mu = s1 * (1.f / 64.f);
  const float inv = rsqrtf(s2 * (1.f / 64.f) - mu * mu + 1e-5f);
  if (val) {
#pragma unroll
    for (int m = 0; m < 4; m++) {
#pragma unroll
      for (int p = 0; p < 2; p++) {
        int f0 = m * 16 + kl * 4 + 2 * p;
        float2 l0 = lns[f0], l1 = lns[f0 + 1];
        float y0 = fmaxf((vv[m][2 * p] - mu) * inv * l0.x + l0.y, 0.f);
        float y1 = fmaxf((vv[m][2 * p + 1] - mu) * inv * l1.x + l1.y, 0.f);
        hn2[(size_t)node * 32 + m * 8 + kl * 2 + p] = pack_h2(y0, y1);
      }
    }
  }
}

// shared macro: LDS counting-sort of this block's bucket into elds/off
#define BUCKET_SORT()                                                       \
  {                                                                         \
    const int n = min(bcur[blockIdx.x * 16], BCAP);                         \
    unsigned ew[6];                                                         \
    _Pragma("unroll") for (int q = 0; q < 6; q++) {                         \
      int j = tid + q * 256;                                                \
      ew[q] = (j < n) ? ebuf[(size_t)blockIdx.x * BCAP + j] : 0xFFFFFFFFu;  \
    }                                                                       \
    __syncthreads();                                                        \
    _Pragma("unroll") for (int q = 0; q < 6; q++) if (ew[q] != 0xFFFFFFFFu) \
        atomicAdd(&cur2[ew[q] & 63], 1);                                    \
    __syncthreads();                                                        \
    if (wave == 0) {                                                        \
      int v = cur2[lane];                                                   \
      int inc = v;                                                          \
      _Pragma("unroll") for (int d = 1; d < 64; d <<= 1) {                  \
        int t = __shfl_up(inc, d, 64);                                      \
        if (lane >= d) inc += t;                                            \
      }                                                                     \
      off[lane + 1] = inc;                                                  \
      if (lane == 0) off[0] = 0;                                            \
      cur2[lane] = inc - v;                                                 \
    }                                                                       \
    __syncthreads();                                                        \
    _Pragma("unroll") for (int q = 0; q < 6; q++) if (ew[q] != 0xFFFFFFFFu) \
        {                                                                   \
      int d = ew[q] & 63;                                                   \
      int p = atomicAdd(&cur2[d], 1);                                       \
      elds[p] = ew[q] >> 6;                                                 \
    }                                                                       \
    __syncthreads();                                                        \
  }

// shared macro: gather into zsb (quarter-wave owns node, batch-8)
#define GATHER()                                                            \
  _Pragma("unroll 1") for (int g = 0; g < 4; g++) {                         \
    const int nl = wave * 16 + g * 4 + qtr;                                 \
    const int node = nbase + nl;                                            \
    const bool valid = node < NN;                                           \
    int j = off[nl];                                                        \
    const int j1 = off[nl + 1];                                             \
    float4 acc = make_float4(0.f, 0.f, 0.f, 0.f);                           \
    if (valid) {                                                            \
      uint2 u = hnv[(size_t)node * 16 + ql];                                \
      float2 f0 = unpack_h2(u.x), f1 = unpack_h2(u.y);                      \
      acc.x = e * f0.x;                                                     \
      acc.y = e * f0.y;                                                     \
      acc.z = e * f1.x;                                                     \
      acc.w = e * f1.y;                                                     \
    }                                                                       \
    for (; j + 8 <= j1; j += 8) {                                           \
      int s_[8];                                                            \
      uint2 u_[8];                                                          \
      _Pragma("unroll") for (int t = 0; t < 8; t++) s_[t] = elds[j + t];    \
      _Pragma("unroll") for (int t = 0; t < 8; t++) u_[t] =                 \
          hnv[(size_t)s_[t] * 16 + ql];                                     \
      _Pragma("unroll") for (int t = 0; t < 8; t++) ACC4(u_[t])             \
    }                                                                       \
    if (j + 4 <= j1) {                                                      \
      int s_[4];                                                            \
      uint2 u_[4];                                                          \
      _Pragma("unroll") for (int t = 0; t < 4; t++) s_[t] = elds[j + t];    \
      _Pragma("unroll") for (int t = 0; t < 4; t++) u_[t] =                 \
          hnv[(size_t)s_[t] * 16 + ql];                                     \
      _Pragma("unroll") for (int t = 0; t < 4; t++) ACC4(u_[t])             \
      j += 4;                                                               \
    }                                                                       \
    for (; j < j1; j++) {                                                   \
      int s = elds[j];                                                      \
      uint2 u = hnv[(size_t)s * 16 + ql];                                   \
      ACC4(u)                                                               \
    }                                                                       \
    uint2 wv;                                                               \
    wv.x = pack_h2(acc.x, acc.y);                                           \
    wv.y = pack_h2(acc.z, acc.w);                                           \
    *(uint2*)(zsb + swz128(nl, ql * 8)) = wv;                               \
  }

// shared macro: MFMA MLP (GEMM1 + bn1/relu + GEMM2 into d0..d3)
#define MLP()                                                               \
  v4f c0 = {0.f, 0.f, 0.f, 0.f}, c1 = c0, c2 = c0, c3 = c0;                 \
  _Pragma("unroll") for (int ks = 0; ks < 4; ks++) {                        \
    uint2 braw = *(const uint2*)(zsb + swz128(zrow, ks * 32 + 8 * kl));     \
    v4h b = __builtin_bit_cast(v4h, braw);                                  \
    const _Float16* wk = w1h + ks * 16 + 4 * kl;                            \
    v4h a0 = *(const v4h*)(wk + (0 * 16 + rl) * HD);                        \
    v4h a1 = *(const v4h*)(wk + (1 * 16 + rl) * HD);                        \
    v4h a2 = *(const v4h*)(wk + (2 * 16 + rl) * HD);                        \
    v4h a3 = *(const v4h*)(wk + (3 * 16 + rl) * HD);                        \
    c0 = __builtin_amdgcn_mfma_f32_16x16x16f16(a0, b, c0, 0, 0, 0);         \
    c1 = __builtin_amdgcn_mfma_f32_16x16x16f16(a1, b, c1, 0, 0, 0);         \
    c2 = __builtin_amdgcn_mfma_f32_16x16x16f16(a2, b, c2, 0, 0, 0);         \
    c3 = __builtin_amdgcn_mfma_f32_16x16x16f16(a3, b, c3, 0, 0, 0);         \
  }                                                                         \
  _Pragma("unroll") for (int m = 0; m < 4; m++) {                           \
    v4f am = (m == 0) ? c0 : (m == 1) ? c1 : (m == 2) ? c2 : c3;            \
    float z[4];                                                             \
    _Pragma("unroll") for (int r = 0; r < 4; r++) {                         \
      int f = m * 16 + kl * 4 + r;                                          \
      float2 ac = acs1[f];                                                  \
      z[r] = fmaxf(fmaf(am[r], ac.x, ac.y), 0.f);                           \
    }                                                                       \
    *(unsigned*)(zsb + swz128(zrow, m * 32 + kl * 8)) = pack_h2(z[0], z[1]);\
    *(unsigned*)(zsb + swz128(zrow, m * 32 + kl * 8 + 4)) =                 \
        pack_h2(z[2], z[3]);                                                \
  }                                                                         \
  v4f d0 = {0.f, 0.f, 0.f, 0.f}, d1 = d0, d2 = d0, d3 = d0;                 \
  _Pragma("unroll") for (int ks = 0; ks < 4; ks++) {                        \
    uint2 braw = *(const uint2*)(zsb + swz128(zrow, ks * 32 + 8 * kl));     \
    v4h b = __builtin_bit_cast(v4h, braw);                                  \
    const _Float16* wk = w2h + ks * 16 + 4 * kl;                            \
    v4h a0 = *(const v4h*)(wk + (0 * 16 + rl) * HD);                        \
    v4h a1 = *(const v4h*)(wk + (1 * 16 + rl) * HD);                        \
    v4h a2 = *(const v4h*)(wk + (2 * 16 + rl) * HD);                        \
    v4h a3 = *(const v4h*)(wk + (3 * 16 + rl) * HD);                        \
    d0 = __builtin_amdgcn_mfma_f32_16x16x16f16(a0, b, d0, 0, 0, 0);         \
    d1 = __builtin_amdgcn_mfma_f32_16x16x16f16(a1, b, d1, 0, 0, 0);         \
    d2 = __builtin_amdgcn_mfma_f32_16x16x16f16(a2, b, d2, 0, 0, 0);         \
    d3 = __builtin_amdgcn_mfma_f32_16x16x16f16(a3, b, d3, 0, 0, 0);         \
  }

#define LAYER_PREAMBLE()                                                    \
  const int tid = threadIdx.x, lane = tid & 63, wave = tid >> 6;            \
  const int rl = lane & 15, kl = lane >> 4;                                 \
  const int qtr = kl, ql = rl;                                              \
  const int nbase = blockIdx.x * 64;                                        \
  const float e = 1.f + eps_arr[layer];                                     \
  const uint2* hnv = (const uint2*)hn2_in;                                  \
  if (tid < 64) {                                                           \
    float a1 = g1[tid] * rsqrtf(v1[tid] + 1e-5f);                           \
    acs1[tid] = make_float2(a1, (b1[tid] - m1[tid]) * a1 + bb1[tid]);       \
    float a2 = g2[tid] * rsqrtf(v2[tid] + 1e-5f);                           \
    acs2[tid] = make_float2(a2, (b2[tid] - m2[tid]) * a2 + bb2[tid]);       \
    cur2[tid] = 0;                                                          \
  }

// ---------- fused layer (layers 0..NL-2): LN epilogue, no atomics ----------
// hn2_in and hn2_out MUST be distinct buffers (cross-block race otherwise).
__global__ __launch_bounds__(256) void k_layer(
    const unsigned* __restrict__ hn2_in, unsigned* __restrict__ hp,
    unsigned* __restrict__ hn2_out, const int* __restrict__ bcur,
    const unsigned* __restrict__ ebuf, const float* __restrict__ eps_arr,
    int layer, const _Float16* __restrict__ w1h, const float* __restrict__ b1,
    const float* __restrict__ g1, const float* __restrict__ bb1,
    const float* __restrict__ m1, const float* __restrict__ v1,
    const _Float16* __restrict__ w2h, const float* __restrict__ b2,
    const float* __restrict__ g2, const float* __restrict__ bb2,
    const float* __restrict__ m2, const float* __restrict__ v2,
    const float* __restrict__ lng, const float* __restrict__ lnb) {
  __shared__ __align__(16) unsigned char zsb[64 * 128];
  __shared__ unsigned elds[BCAP];
  __shared__ int off[65];
  __shared__ int cur2[64];
  __shared__ float2 acs1[64], acs2[64], lns[64];
  LAYER_PREAMBLE()
  if (tid < 64) lns[tid] = make_float2(lng[tid], lnb[tid]);
  BUCKET_SORT()
  GATHER()
  const int zrow = wave * 16 + rl;
  MLP()

  // epilogue: bn2+relu, residual (f16 h), store hp, LN+relu, store hn2_out
  const int node = nbase + zrow;
  const bool val = node < NN;
  float vv[4][4];
  float s1 = 0.f, s2 = 0.f;
#pragma unroll
  for (int m = 0; m < 4; m++) {
    v4f am = (m == 0) ? d0 : (m == 1) ? d1 : (m == 2) ? d2 : d3;
    float hv[4] = {0.f, 0.f, 0.f, 0.f};
    if (val) {
      uint2 hraw = *(const uint2*)(hp + (size_t)node * 32 + m * 8 + kl * 2);
      float2 ha = unpack_h2(hraw.x), hb = unpack_h2(hraw.y);
      hv[0] = ha.x;
      hv[1] = ha.y;
      hv[2] = hb.x;
      hv[3] = hb.y;
    }
#pragma unroll
    for (int r = 0; r < 4; r++) {
      int f = m * 16 + kl * 4 + r;
      float2 ac = acs2[f];
      float z2 = fmaxf(fmaf(am[r], ac.x, ac.y), 0.f);
      float v = hv[r] + z2;
      vv[m][r] = v;
      s1 += v;
      s2 += v * v;
    }
    if (val) {
      uint2 st;
      st.x = pack_h2(vv[m][0], vv[m][1]);
      st.y = pack_h2(vv[m][2], vv[m][3]);
      *(uint2*)(hp + (size_t)node * 32 + m * 8 + kl * 2) = st;
    }
  }
  s1 += __shfl_xor(s1, 16, 64);
  s1 += __shfl_xor(s1, 32, 64);
  s2 += __shfl_xor(s2, 16, 64);
  s2 += __shfl_xor(s2, 32, 64);
  const float mu = s1 * (1.f / 64.f);
  const float inv = rsqrtf(s2 * (1.f / 64.f) - mu * mu + 1e-5f);
  if (val) {
#pragma unroll
    for (int m = 0; m < 4; m++) {
#pragma unroll
      for (int p = 0; p < 2; p++) {
        int f0 = m * 16 + kl * 4 + 2 * p;
        float2 l0 = lns[f0], l1 = lns[f0 + 1];
        float y0 = fmaxf((vv[m][2 * p] - mu) * inv * l0.x + l0.y, 0.f);
        float y1 = fmaxf((vv[m][2 * p + 1] - mu) * inv * l1.x + l1.y, 0.f);
        hn2_out[(size_t)node * 32 + m * 8 + kl * 2 + p] = pack_h2(y0, y1);
      }
    }
  }
}

// ---------- last layer: no LN, no hn2_out, no atomics; writes hp only ------
__global__ __launch_bounds__(256) void k_layer3(
    const unsigned* __restrict__ hn2_in, unsigned* __restrict__ hp,
    const int* __restrict__ bcur, const unsigned* __restrict__ ebuf,
    const float* __restrict__ eps_arr, int layer,
    const _Float16* __restrict__ w1h, const float* __restrict__ b1,
    const float* __restrict__ g1, const float* __restrict__ bb1,
    const float* __restrict__ m1, const float* __restrict__ v1,
    const _Float16* __restrict__ w2h, const float* __restrict__ b2,
    const float* __restrict__ g2, const float* __restrict__ bb2,
    const float* __restrict__ m2, const float* __restrict__ v2) {
  __shared__ __align__(16) unsigned char zsb[64 * 128];
  __shared__ unsigned elds[BCAP];
  __shared__ int off[65];
  __shared__ int cur2[64];
  __shared__ float2 acs1[64], acs2[64];
  LAYER_PREAMBLE()
  BUCKET_SORT()
  GATHER()
  const int zrow = wave * 16 + rl;
  MLP()

  const int node = nbase + zrow;
  const bool val = node < NN;
#pragma unroll
  for (int m = 0; m < 4; m++) {
    v4f am = (m == 0) ? d0 : (m == 1) ? d1 : (m == 2) ? d2 : d3;
    float hv[4] = {0.f, 0.f, 0.f, 0.f};
    if (val) {
      uint2 hraw = *(const uint2*)(hp + (size_t)node * 32 + m * 8 + kl * 2);
      float2 ha = unpack_h2(hraw.x), hb = unpack_h2(hraw.y);
      hv[0] = ha.x;
      hv[1] = ha.y;
      hv[2] = hb.x;
      hv[3] = hb.y;
    }
    float vv[4];
#pragma unroll
    for (int r = 0; r < 4; r++) {
      int f = m * 16 + kl * 4 + r;
      float2 ac = acs2[f];
      float z2 = fmaxf(fmaf(am[r], ac.x, ac.y), 0.f);
      vv[r] = hv[r] + z2;
    }
    if (val) {
      uint2 st;
      st.x = pack_h2(vv[0], vv[1]);
      st.y = pack_h2(vv[2], vv[3]);
      *(uint2*)(hp + (size_t)node * 32 + m * 8 + kl * 2) = st;
    }
  }
}

// ---------- pooling (h in f16) ----------
__global__ __launch_bounds__(256) void k_pool(const unsigned* __restrict__ hp,
                                              const int* __restrict__ batch,
                                              float* __restrict__ sums) {
  const int lane = threadIdx.x & 63;
  const int gw = blockIdx.x * 4 + (threadIdx.x >> 6);
  const int base = gw * 64;
  if (base >= NN) return;
  const int end = min(base + 64, NN);
  float acc = 0.f;
  int cur = batch[base];
  for (int n = base; n < end; n++) {
    int g = batch[n];
    if (g != cur) {
      atomicAdd(&sums[cur * HD + lane], acc);
      acc = 0.f;
      cur = g;
    }
    unsigned u = hp[(size_t)n * 32 + (lane >> 1)];
    float2 f = unpack_h2(u);
    acc += (lane & 1) ? f.y : f.x;
  }
  atomicAdd(&sums[cur * HD + lane], acc);
}

__global__ __launch_bounds__(256) void k_div(const float* __restrict__ sums,
                                             const float* __restrict__ cnt,
                                             float* __restrict__ out) {
  int i = blockIdx.x * 256 + threadIdx.x;
  if (i < NG * HD) out[i] = sums[i] / fmaxf(cnt[i >> 6], 1.f);
}

// ---------- launch ----------
extern "C" void kernel_launch(void* const* d_in, const int* in_sizes, int n_in,
                              void* d_out, int out_size, void* d_ws,
                              size_t ws_size, hipStream_t stream) {
  const float* x = (const float*)d_in[0];
  const float* node_w = (const float*)d_in[1];
  const float* node_b = (const float*)d_in[2];
  const float* ln_g = (const float*)d_in[3];
  const float* ln_b = (const float*)d_in[4];
  const float* eps = (const float*)d_in[5];
  const float* w1 = (const float*)d_in[6];
  const float* b1 = (const float*)d_in[7];
  const float* bn1_g = (const float*)d_in[8];
  const float* bn1_b = (const float*)d_in[9];
  const float* bn1_m = (const float*)d_in[10];
  const float* bn1_v = (const float*)d_in[11];
  const float* w2 = (const float*)d_in[12];
  const float* b2 = (const float*)d_in[13];
  const float* bn2_g = (const float*)d_in[14];
  const float* bn2_b = (const float*)d_in[15];
  const float* bn2_m = (const float*)d_in[16];
  const float* bn2_v = (const float*)d_in[17];
  const int* edge_index = (const int*)d_in[18];
  const int* batch = (const int*)d_in[19];
  float* out = (float*)d_out;

  char* ws = (char*)d_ws;
  size_t off = 0;
  auto carve = [&](size_t bytes) {
    void* p = ws + off;
    off += (bytes + 255) & ~(size_t)255;
    return p;
  };
  unsigned* hp = (unsigned*)carve((size_t)NN * 32 * sizeof(unsigned));
  unsigned* hn2a = (unsigned*)carve((size_t)NN * 32 * sizeof(unsigned));
  unsigned* hn2b = (unsigned*)carve((size_t)NN * 32 * sizeof(unsigned));
  unsigned* ebuf = (unsigned*)carve((size_t)NBUCK * BCAP * sizeof(unsigned));
  unsigned* ebufA = (unsigned*)carve((size_t)NBIN * BINCAP * sizeof(unsigned));
  int* bcur = (int*)carve((size_t)NBUCK * 16 * sizeof(int));
  int* acur = (int*)carve((size_t)NBIN * 16 * sizeof(int));
  float* sums = (float*)carve((size_t)NG * HD * sizeof(float));
  float* cnt = (float*)carve((size_t)NG * sizeof(float));
  _Float16* wenc = (_Float16*)carve((size_t)HD * DIN * sizeof(_Float16));
  _Float16* w1h = (_Float16*)carve((size_t)NL * HD * HD * sizeof(_Float16));
  _Float16* w2h = (_Float16*)carve((size_t)NL * HD * HD * sizeof(_Float16));

  const int* e_src = edge_index;
  const int* e_dst = edge_index + NE;

  k_wconv<<<(NBUCK * 16 + 255) / 256, 256, 0, stream>>>(
      node_w, w1, w2, batch, wenc, w1h, w2h, bcur, acur, sums, cnt);
  k_binA<<<BINA_BLOCKS, 256, 0, stream>>>(e_src, e_dst, acur, ebufA);
  k_binB_enc<<<NBIN * SB + NBENC, 256, 0, stream>>>(acur, ebufA, bcur, ebuf,
                                                    x, wenc, node_b, ln_g,
                                                    ln_b, hp, hn2a);

  for (int l = 0; l < NL - 1; l++) {
    const unsigned* hin = (l & 1) ? hn2b : hn2a;
    unsigned* hout = (l & 1) ? hn2a : hn2b;
    k_layer<<<NBUCK, 256, 0, stream>>>(
        hin, hp, hout, bcur, ebuf, eps, l, w1h + (size_t)l * HD * HD,
        b1 + l * HD, bn1_g + l * HD, bn1_b + l * HD, bn1_m + l * HD,
        bn1_v + l * HD, w2h + (size_t)l * HD * HD, b2 + l * HD, bn2_g + l * HD,
        bn2_b + l * HD, bn2_m + l * HD, bn2_v + l * HD, ln_g + (l + 1) * HD,
        ln_b + (l + 1) * HD);
  }
  {
    const int l = NL - 1;
    const unsigned* hin = (l & 1) ? hn2b : hn2a;
    k_layer3<<<NBUCK, 256, 0, stream>>>(
        hin, hp, bcur, ebuf, eps, l, w1h + (size_t)l * HD * HD, b1 + l * HD,
        bn1_g + l * HD, bn1_b + l * HD, bn1_m + l * HD, bn1_v + l * HD,
        w2h + (size_t)l * HD * HD, b2 + l * HD, bn2_g + l * HD, bn2_b + l * HD,
        bn2_m + l * HD, bn2_v + l * HD);
  }

  k_pool<<<(NN + 255) / 256, 256, 0, stream>>>(hp, batch, sums);
  k_div<<<(NG * HD + 255) / 256, 256, 0, stream>>>(sums, cnt, out);
}

// Round 20
// 351.535 us; speedup vs baseline: 1.2012x; 1.0853x over previous
//
#include <hip/hip_runtime.h>
#include <hip/hip_fp16.h>

#define NN 100000
#define NE 1600000
#define DIN 128
#define HD 64
#define NL 4
#define NG 64
#define NBUCK ((NN + 63) / 64)  // 1563 buckets of 64 dst nodes
#define NBENC NBUCK             // encoder blocks
#define BCAP 1536               // per-bucket edge capacity (mean 1024, +16 sigma)
#define NBIN 98                 // coarse bins of 1024 dst nodes
#define BINCAP 18000            // words per coarse bin (mean 16327, +13 sigma)
#define BINA_BLOCKS 512
#define BT 2048                 // binB LDS tile words
#define SB 4                    // binB slices per bin (parallelize the tail)

typedef _Float16 v4h __attribute__((ext_vector_type(4)));
typedef float v4f __attribute__((ext_vector_type(4)));

// ---------- helpers ----------
__device__ __forceinline__ float2 unpack_h2(unsigned w) {
  __half2 hh = *reinterpret_cast<__half2*>(&w);
  return __half22float2(hh);
}
__device__ __forceinline__ unsigned pack_h2(float a, float b) {
  __half2 hh = __floats2half2_rn(a, b);
  return *reinterpret_cast<unsigned*>(&hh);
}
// fp8 e4m3 (OCP on gfx950) 4-pack converts
__device__ __forceinline__ unsigned pack_fp8x4(float a, float b, float c,
                                               float d) {
  int w = __builtin_amdgcn_cvt_pk_fp8_f32(a, b, 0, false);
  w = __builtin_amdgcn_cvt_pk_fp8_f32(c, d, w, true);
  return (unsigned)w;
}
// swizzled byte addr in f16 LDS tile, row stride 128 B (HD=64 f16)
__device__ __forceinline__ int swz128(int row, int colb) {
  return row * 128 + (colb ^ ((row & 7) << 4));
}
// row stride 256 B (DIN=128 f16)
__device__ __forceinline__ int swz256(int row, int colb) {
  return row * 256 + (colb ^ ((row & 7) << 4));
}

// ---------- weight conversion + zero-init + cnt (binary search, race-free) --
__global__ __launch_bounds__(256) void k_wconv(
    const float* __restrict__ nodew, const float* __restrict__ w1,
    const float* __restrict__ w2, const int* __restrict__ batch,
    _Float16* __restrict__ wenc, _Float16* __restrict__ w1h,
    _Float16* __restrict__ w2h, int* __restrict__ bcur,
    int* __restrict__ acur, float* __restrict__ sums,
    float* __restrict__ cnt) {
  int i = blockIdx.x * 256 + threadIdx.x;
  if (i < HD * DIN) wenc[i] = (_Float16)nodew[i];
  if (i < NL * HD * HD) {
    w1h[i] = (_Float16)w1[i];
    w2h[i] = (_Float16)w2[i];
  }
  if (i < NBUCK * 16) bcur[i] = 0;  // padded cursors (1 line apart)
  if (i < NBIN * 16) acur[i] = 0;
  if (i < NG * HD) sums[i] = 0.f;
  if (i < NG) {  // cnt[g] via binary search on sorted batch
    int lo = 0, hi = NN;
    while (lo < hi) {
      int mid = (lo + hi) >> 1;
      if (batch[mid] < i) lo = mid + 1;
      else hi = mid;
    }
    int start = lo;
    lo = 0; hi = NN;
    while (lo < hi) {
      int mid = (lo + hi) >> 1;
      if (batch[mid] < i + 1) lo = mid + 1;
      else hi = mid;
    }
    cnt[i] = (float)(lo - start);
  }
}

// ---------- pass A: LDS-chunked coarse binning (256B coalesced flushes) ----
// word = (src<<10) | (dst & 1023), bin = dst >> 10.
__global__ __launch_bounds__(256) void k_binA(const int* __restrict__ src,
                                              const int* __restrict__ dst,
                                              int* __restrict__ acur,
                                              unsigned* __restrict__ ebufA) {
  __shared__ unsigned lbuf[NBIN][96];
  __shared__ int lcnt[NBIN];
  const int tid = threadIdx.x, lane = tid & 63, wave = tid >> 6;
  for (int b = tid; b < NBIN; b += 256) lcnt[b] = 0;
  __syncthreads();

  const int tiles = NE / 512;  // 3125 exact
  for (int t = blockIdx.x; t < tiles; t += gridDim.x) {
#pragma unroll
    for (int q = 0; q < 2; q++) {
      const int e = t * 512 + q * 256 + tid;
      const int d = dst[e], s = src[e];
      const int b = d >> 10;
      const unsigned w = ((unsigned)s << 10) | (unsigned)(d & 1023);
      int p = atomicAdd(&lcnt[b], 1);
      if (p < 96) {
        lbuf[b][p] = w;
      } else {  // statistically negligible overflow: direct global append
        int gp = atomicAdd(&acur[b * 16], 1);
        if (gp < BINCAP) ebufA[(size_t)b * BINCAP + gp] = w;
      }
    }
    __syncthreads();
    // flush full 64-word (256B) chunks; wave v owns bins v, v+4, ...
    for (int bb = wave; bb < NBIN; bb += 4) {
      int n = min(lcnt[bb], 96);
      if (n >= 64) {
        int gp = 0;
        if (lane == 0) gp = atomicAdd(&acur[bb * 16], 64);
        gp = __shfl(gp, 0, 64);
        if (gp + lane < BINCAP)
          ebufA[(size_t)bb * BINCAP + gp + lane] = lbuf[bb][lane];
        int r = n - 64;  // <= 32
        unsigned tmp = (lane < r) ? lbuf[bb][64 + lane] : 0u;
        if (lane < r) lbuf[bb][lane] = tmp;
        lcnt[bb] = r;
      }
    }
    __syncthreads();
  }
  // final flush of remainders (< 96 words per bin)
  for (int bb = wave; bb < NBIN; bb += 4) {
    int n = min(lcnt[bb], 96);
    if (n > 0) {
      int gp = 0;
      if (lane == 0) gp = atomicAdd(&acur[bb * 16], n);
      gp = __shfl(gp, 0, 64);
      if (lane < n && gp + lane < BINCAP)
        ebufA[(size_t)bb * BINCAP + gp + lane] = lbuf[bb][lane];
      if (n > 64 && 64 + lane < n && gp + 64 + lane < BINCAP)
        ebufA[(size_t)bb * BINCAP + gp + 64 + lane] = lbuf[bb][64 + lane];
    }
  }
}

// fp8 unpack-accumulate: U is one uint = 4 fp8 features
#define ACC4(U)                                                      \
  {                                                                  \
    auto lo = __builtin_amdgcn_cvt_pk_f32_fp8((int)(U), false);      \
    auto hi = __builtin_amdgcn_cvt_pk_f32_fp8((int)(U), true);       \
    acc.x += lo[0];                                                  \
    acc.y += lo[1];                                                  \
    acc.z += hi[0];                                                  \
    acc.w += hi[1];                                                  \
  }

// ---------- fused dispatch: binB slices (blocks 0..NBIN*SB-1) | encoder ----
__global__ __launch_bounds__(256) void k_binB_enc(
    const int* __restrict__ acur, const unsigned* __restrict__ ebufA,
    int* __restrict__ bcur, unsigned* __restrict__ ebuf,
    const float* __restrict__ x, const _Float16* __restrict__ wenc,
    const float* __restrict__ bias, const float* __restrict__ lng,
    const float* __restrict__ lnb, unsigned* __restrict__ hp,
    unsigned* __restrict__ hn8) {
  __shared__ __align__(16) unsigned char smem[17152];
  const int tid = threadIdx.x, lane = tid & 63, wave = tid >> 6;

  if (blockIdx.x < NBIN * SB) {
    // ----- binB: LDS tile-sort coarse-bin slice -> final buckets -----
    unsigned* raw = (unsigned*)smem;               // 8192 B
    unsigned* srt = (unsigned*)(smem + 8192);      // 8192 B
    int* hist = (int*)(smem + 16384);
    int* hoff = (int*)(smem + 16448);
    int* hcur = (int*)(smem + 16512);
    int* gbase = (int*)(smem + 16576);
    const int b = blockIdx.x / SB, sl = blockIdx.x % SB;
    const int n = min(acur[b * 16], BINCAP);
    const int per = (n + SB - 1) / SB;
    const int j0 = sl * per, j1 = min(j0 + per, n);

    for (int t0 = j0; t0 < j1; t0 += BT) {
      const int tn = min(BT, j1 - t0);
      if (tid < 16) hist[tid] = 0;
      __syncthreads();
      for (int j = tid; j < tn; j += 256) {
        unsigned w = ebufA[(size_t)b * BINCAP + t0 + j];
        raw[j] = w;
        atomicAdd(&hist[(w >> 6) & 15], 1);  // bucket-local = dst bits 6..9
      }
      __syncthreads();
      if (tid == 0) {
        int run = 0;
#pragma unroll
        for (int q = 0; q < 16; q++) {
          hoff[q] = run;
          hcur[q] = run;
          run += hist[q];
        }
      }
      __syncthreads();
      if (tid < 16)
        gbase[tid] = atomicAdd(&bcur[(b * 16 + tid) * 16], hist[tid]);
      __syncthreads();
      for (int j = tid; j < tn; j += 256) {
        unsigned w = raw[j];
        int p = atomicAdd(&hcur[(w >> 6) & 15], 1);
        srt[p] = w;
      }
      __syncthreads();
      for (int q = wave; q < 16; q += 4) {
        const int cntq = hist[q], bs = hoff[q], gb = gbase[q];
        const size_t base = (size_t)(b * 16 + q) * BCAP;
        for (int j = lane; j < cntq; j += 64) {
          int p = gb + j;
          unsigned w = srt[bs + j];
          if (p < BCAP) ebuf[base + p] = ((w >> 10) << 6) | (w & 63u);
        }
      }
      __syncthreads();
    }
    return;
  }

  // ----- encoder: h(f16) = x @ W^T + b ; hn8 = fp8(relu(LN_0(h))) -----
  unsigned char* xsb = smem;                       // 16384 B
  float* bias_s = (float*)(smem + 16384);          // 256 B
  float2* lns = (float2*)(smem + 16640);           // 512 B
  const int rl = lane & 15, kl = lane >> 4;
  const int nbase = (blockIdx.x - NBIN * SB) * 64;

  if (tid < 64) {
    bias_s[tid] = bias[tid];
    lns[tid] = make_float2(lng[tid], lnb[tid]);
  }
  __syncthreads();

#pragma unroll 1
  for (int rr16 = 0; rr16 < 16; rr16++) {
    const int rr = wave * 16 + rr16;
    const int node = nbase + rr;
    float2 xv = make_float2(0.f, 0.f);
    if (node < NN) xv = *(const float2*)(x + (size_t)node * DIN + 2 * lane);
    *(unsigned*)(xsb + swz256(rr, 4 * lane)) = pack_h2(xv.x, xv.y);
  }
  // wave-local rows -> no barrier

  const int zrow = wave * 16 + rl;
  v4f c0 = {0.f, 0.f, 0.f, 0.f}, c1 = c0, c2 = c0, c3 = c0;
#pragma unroll
  for (int ks = 0; ks < DIN / 16; ks++) {
    uint2 braw = *(const uint2*)(xsb + swz256(zrow, ks * 32 + 8 * kl));
    v4h b = __builtin_bit_cast(v4h, braw);
    const _Float16* wk = wenc + ks * 16 + 4 * kl;
    v4h a0 = *(const v4h*)(wk + (0 * 16 + rl) * DIN);
    v4h a1 = *(const v4h*)(wk + (1 * 16 + rl) * DIN);
    v4h a2 = *(const v4h*)(wk + (2 * 16 + rl) * DIN);
    v4h a3 = *(const v4h*)(wk + (3 * 16 + rl) * DIN);
    c0 = __builtin_amdgcn_mfma_f32_16x16x16f16(a0, b, c0, 0, 0, 0);
    c1 = __builtin_amdgcn_mfma_f32_16x16x16f16(a1, b, c1, 0, 0, 0);
    c2 = __builtin_amdgcn_mfma_f32_16x16x16f16(a2, b, c2, 0, 0, 0);
    c3 = __builtin_amdgcn_mfma_f32_16x16x16f16(a3, b, c3, 0, 0, 0);
  }

  const int node = nbase + zrow;
  const bool val = node < NN;
  float vv[4][4];
  float s1 = 0.f, s2 = 0.f;
#pragma unroll
  for (int m = 0; m < 4; m++) {
    v4f am = (m == 0) ? c0 : (m == 1) ? c1 : (m == 2) ? c2 : c3;
#pragma unroll
    for (int r = 0; r < 4; r++) {
      int f = m * 16 + kl * 4 + r;
      float v = am[r] + bias_s[f];
      vv[m][r] = v;
      s1 += v;
      s2 += v * v;
    }
    if (val) {
      uint2 st;
      st.x = pack_h2(vv[m][0], vv[m][1]);
      st.y = pack_h2(vv[m][2], vv[m][3]);
      *(uint2*)(hp + (size_t)node * 32 + m * 8 + kl * 2) = st;
    }
  }
  s1 += __shfl_xor(s1, 16, 64);
  s1 += __shfl_xor(s1, 32, 64);
  s2 += __shfl_xor(s2, 16, 64);
  s2 += __shfl_xor(s2, 32, 64);
  const float mu = s1 * (1.f / 64.f);
  const float inv = rsqrtf(s2 * (1.f / 64.f) - mu * mu + 1e-5f);
  if (val) {
#pragma unroll
    for (int m = 0; m < 4; m++) {
      float y[4];
#pragma unroll
      for (int r = 0; r < 4; r++) {
        int f = m * 16 + kl * 4 + r;
        float2 l = lns[f];
        y[r] = fmaxf((vv[m][r] - mu) * inv * l.x + l.y, 0.f);
      }
      hn8[(size_t)node * 16 + m * 4 + kl] = pack_fp8x4(y[0], y[1], y[2], y[3]);
    }
  }
}

// shared macro: LDS counting-sort of this block's bucket into elds/off
#define BUCKET_SORT()                                                       \
  {                                                                         \
    const int n = min(bcur[blockIdx.x * 16], BCAP);                         \
    unsigned ew[6];                                                         \
    _Pragma("unroll") for (int q = 0; q < 6; q++) {                         \
      int j = tid + q * 256;                                                \
      ew[q] = (j < n) ? ebuf[(size_t)blockIdx.x * BCAP + j] : 0xFFFFFFFFu;  \
    }                                                                       \
    __syncthreads();                                                        \
    _Pragma("unroll") for (int q = 0; q < 6; q++) if (ew[q] != 0xFFFFFFFFu) \
        atomicAdd(&cur2[ew[q] & 63], 1);                                    \
    __syncthreads();                                                        \
    if (wave == 0) {                                                        \
      int v = cur2[lane];                                                   \
      int inc = v;                                                          \
      _Pragma("unroll") for (int d = 1; d < 64; d <<= 1) {                  \
        int t = __shfl_up(inc, d, 64);                                      \
        if (lane >= d) inc += t;                                            \
      }                                                                     \
      off[lane + 1] = inc;                                                  \
      if (lane == 0) off[0] = 0;                                            \
      cur2[lane] = inc - v;                                                 \
    }                                                                       \
    __syncthreads();                                                        \
    _Pragma("unroll") for (int q = 0; q < 6; q++) if (ew[q] != 0xFFFFFFFFu) \
        {                                                                   \
      int d = ew[q] & 63;                                                   \
      int p = atomicAdd(&cur2[d], 1);                                       \
      elds[p] = ew[q] >> 6;                                                 \
    }                                                                       \
    __syncthreads();                                                        \
  }

// shared macro: gather into zsb (quarter-wave owns node, batch-8; fp8 rows,
// one 64B line per edge)
#define GATHER()                                                            \
  _Pragma("unroll 1") for (int g = 0; g < 4; g++) {                         \
    const int nl = wave * 16 + g * 4 + qtr;                                 \
    const int node = nbase + nl;                                            \
    const bool valid = node < NN;                                           \
    int j = off[nl];                                                        \
    const int j1 = off[nl + 1];                                             \
    float4 acc = make_float4(0.f, 0.f, 0.f, 0.f);                           \
    if (valid) {                                                            \
      unsigned u = hn8[(size_t)node * 16 + ql];                             \
      auto lo = __builtin_amdgcn_cvt_pk_f32_fp8((int)u, false);             \
      auto hi = __builtin_amdgcn_cvt_pk_f32_fp8((int)u, true);              \
      acc.x = e * lo[0];                                                    \
      acc.y = e * lo[1];                                                    \
      acc.z = e * hi[0];                                                    \
      acc.w = e * hi[1];                                                    \
    }                                                                       \
    for (; j + 8 <= j1; j += 8) {                                           \
      int s_[8];                                                            \
      unsigned u_[8];                                                       \
      _Pragma("unroll") for (int t = 0; t < 8; t++) s_[t] = elds[j + t];    \
      _Pragma("unroll") for (int t = 0; t < 8; t++) u_[t] =                 \
          hn8[(size_t)s_[t] * 16 + ql];                                     \
      _Pragma("unroll") for (int t = 0; t < 8; t++) ACC4(u_[t])             \
    }                                                                       \
    if (j + 4 <= j1) {                                                      \
      int s_[4];                                                            \
      unsigned u_[4];                                                       \
      _Pragma("unroll") for (int t = 0; t < 4; t++) s_[t] = elds[j + t];    \
      _Pragma("unroll") for (int t = 0; t < 4; t++) u_[t] =                 \
          hn8[(size_t)s_[t] * 16 + ql];                                     \
      _Pragma("unroll") for (int t = 0; t < 4; t++) ACC4(u_[t])             \
      j += 4;                                                               \
    }                                                                       \
    for (; j < j1; j++) {                                                   \
      int s = elds[j];                                                      \
      unsigned u = hn8[(size_t)s * 16 + ql];                                \
      ACC4(u)                                                               \
    }                                                                       \
    uint2 wv;                                                               \
    wv.x = pack_h2(acc.x, acc.y);                                           \
    wv.y = pack_h2(acc.z, acc.w);                                           \
    *(uint2*)(zsb + swz128(nl, ql * 8)) = wv;                               \
  }

// shared macro: MFMA MLP (GEMM1 + bn1/relu + GEMM2 into d0..d3)
#define MLP()                                                               \
  v4f c0 = {0.f, 0.f, 0.f, 0.f}, c1 = c0, c2 = c0, c3 = c0;                 \
  _Pragma("unroll") for (int ks = 0; ks < 4; ks++) {                        \
    uint2 braw = *(const uint2*)(zsb + swz128(zrow, ks * 32 + 8 * kl));     \
    v4h b = __builtin_bit_cast(v4h, braw);                                  \
    const _Float16* wk = w1h + ks * 16 + 4 * kl;                            \
    v4h a0 = *(const v4h*)(wk + (0 * 16 + rl) * HD);                        \
    v4h a1 = *(const v4h*)(wk + (1 * 16 + rl) * HD);                        \
    v4h a2 = *(const v4h*)(wk + (2 * 16 + rl) * HD);                        \
    v4h a3 = *(const v4h*)(wk + (3 * 16 + rl) * HD);                        \
    c0 = __builtin_amdgcn_mfma_f32_16x16x16f16(a0, b, c0, 0, 0, 0);         \
    c1 = __builtin_amdgcn_mfma_f32_16x16x16f16(a1, b, c1, 0, 0, 0);         \
    c2 = __builtin_amdgcn_mfma_f32_16x16x16f16(a2, b, c2, 0, 0, 0);         \
    c3 = __builtin_amdgcn_mfma_f32_16x16x16f16(a3, b, c3, 0, 0, 0);         \
  }                                                                         \
  _Pragma("unroll") for (int m = 0; m < 4; m++) {                           \
    v4f am = (m == 0) ? c0 : (m == 1) ? c1 : (m == 2) ? c2 : c3;            \
    float z[4];                                                             \
    _Pragma("unroll") for (int r = 0; r < 4; r++) {                         \
      int f = m * 16 + kl * 4 + r;                                          \
      float2 ac = acs1[f];                                                  \
      z[r] = fmaxf(fmaf(am[r], ac.x, ac.y), 0.f);                           \
    }                                                                       \
    *(unsigned*)(zsb + swz128(zrow, m * 32 + kl * 8)) = pack_h2(z[0], z[1]);\
    *(unsigned*)(zsb + swz128(zrow, m * 32 + kl * 8 + 4)) =                 \
        pack_h2(z[2], z[3]);                                                \
  }                                                                         \
  v4f d0 = {0.f, 0.f, 0.f, 0.f}, d1 = d0, d2 = d0, d3 = d0;                 \
  _Pragma("unroll") for (int ks = 0; ks < 4; ks++) {                        \
    uint2 braw = *(const uint2*)(zsb + swz128(zrow, ks * 32 + 8 * kl));     \
    v4h b = __builtin_bit_cast(v4h, braw);                                  \
    const _Float16* wk = w2h + ks * 16 + 4 * kl;                            \
    v4h a0 = *(const v4h*)(wk + (0 * 16 + rl) * HD);                        \
    v4h a1 = *(const v4h*)(wk + (1 * 16 + rl) * HD);                        \
    v4h a2 = *(const v4h*)(wk + (2 * 16 + rl) * HD);                        \
    v4h a3 = *(const v4h*)(wk + (3 * 16 + rl) * HD);                        \
    d0 = __builtin_amdgcn_mfma_f32_16x16x16f16(a0, b, d0, 0, 0, 0);         \
    d1 = __builtin_amdgcn_mfma_f32_16x16x16f16(a1, b, d1, 0, 0, 0);         \
    d2 = __builtin_amdgcn_mfma_f32_16x16x16f16(a2, b, d2, 0, 0, 0);         \
    d3 = __builtin_amdgcn_mfma_f32_16x16x16f16(a3, b, d3, 0, 0, 0);         \
  }

#define LAYER_PREAMBLE()                                                    \
  const int tid = threadIdx.x, lane = tid & 63, wave = tid >> 6;            \
  const int rl = lane & 15, kl = lane >> 4;                                 \
  const int qtr = kl, ql = rl;                                              \
  const int nbase = blockIdx.x * 64;                                        \
  const float e = 1.f + eps_arr[layer];                                     \
  const unsigned* hn8 = hn8_in;                                             \
  if (tid < 64) {                                                           \
    float a1 = g1[tid] * rsqrtf(v1[tid] + 1e-5f);                           \
    acs1[tid] = make_float2(a1, (b1[tid] - m1[tid]) * a1 + bb1[tid]);       \
    float a2 = g2[tid] * rsqrtf(v2[tid] + 1e-5f);                           \
    acs2[tid] = make_float2(a2, (b2[tid] - m2[tid]) * a2 + bb2[tid]);       \
    cur2[tid] = 0;                                                          \
  }

// ---------- fused layer (layers 0..NL-2): LN epilogue, no atomics ----------
// hn8_in and hn8_out MUST be distinct buffers (cross-block race otherwise).
__global__ __launch_bounds__(256) void k_layer(
    const unsigned* __restrict__ hn8_in, unsigned* __restrict__ hp,
    unsigned* __restrict__ hn8_out, const int* __restrict__ bcur,
    const unsigned* __restrict__ ebuf, const float* __restrict__ eps_arr,
    int layer, const _Float16* __restrict__ w1h, const float* __restrict__ b1,
    const float* __restrict__ g1, const float* __restrict__ bb1,
    const float* __restrict__ m1, const float* __restrict__ v1,
    const _Float16* __restrict__ w2h, const float* __restrict__ b2,
    const float* __restrict__ g2, const float* __restrict__ bb2,
    const float* __restrict__ m2, const float* __restrict__ v2,
    const float* __restrict__ lng, const float* __restrict__ lnb) {
  __shared__ __align__(16) unsigned char zsb[64 * 128];
  __shared__ unsigned elds[BCAP];
  __shared__ int off[65];
  __shared__ int cur2[64];
  __shared__ float2 acs1[64], acs2[64], lns[64];
  LAYER_PREAMBLE()
  if (tid < 64) lns[tid] = make_float2(lng[tid], lnb[tid]);
  BUCKET_SORT()
  GATHER()
  const int zrow = wave * 16 + rl;
  MLP()

  // epilogue: bn2+relu, residual (f16 h), store hp, LN+relu, store hn8_out
  const int node = nbase + zrow;
  const bool val = node < NN;
  float vv[4][4];
  float s1 = 0.f, s2 = 0.f;
#pragma unroll
  for (int m = 0; m < 4; m++) {
    v4f am = (m == 0) ? d0 : (m == 1) ? d1 : (m == 2) ? d2 : d3;
    float hv[4] = {0.f, 0.f, 0.f, 0.f};
    if (val) {
      uint2 hraw = *(const uint2*)(hp + (size_t)node * 32 + m * 8 + kl * 2);
      float2 ha = unpack_h2(hraw.x), hb = unpack_h2(hraw.y);
      hv[0] = ha.x;
      hv[1] = ha.y;
      hv[2] = hb.x;
      hv[3] = hb.y;
    }
#pragma unroll
    for (int r = 0; r < 4; r++) {
      int f = m * 16 + kl * 4 + r;
      float2 ac = acs2[f];
      float z2 = fmaxf(fmaf(am[r], ac.x, ac.y), 0.f);
      float v = hv[r] + z2;
      vv[m][r] = v;
      s1 += v;
      s2 += v * v;
    }
    if (val) {
      uint2 st;
      st.x = pack_h2(vv[m][0], vv[m][1]);
      st.y = pack_h2(vv[m][2], vv[m][3]);
      *(uint2*)(hp + (size_t)node * 32 + m * 8 + kl * 2) = st;
    }
  }
  s1 += __shfl_xor(s1, 16, 64);
  s1 += __shfl_xor(s1, 32, 64);
  s2 += __shfl_xor(s2, 16, 64);
  s2 += __shfl_xor(s2, 32, 64);
  const float mu = s1 * (1.f / 64.f);
  const float inv = rsqrtf(s2 * (1.f / 64.f) - mu * mu + 1e-5f);
  if (val) {
#pragma unroll
    for (int m = 0; m < 4; m++) {
      float y[4];
#pragma unroll
      for (int r = 0; r < 4; r++) {
        int f = m * 16 + kl * 4 + r;
        float2 l = lns[f];
        y[r] = fmaxf((vv[m][r] - mu) * inv * l.x + l.y, 0.f);
      }
      hn8_out[(size_t)node * 16 + m * 4 + kl] =
          pack_fp8x4(y[0], y[1], y[2], y[3]);
    }
  }
}

// ---------- last layer: no LN, no hn8_out, no atomics; writes hp only ------
__global__ __launch_bounds__(256) void k_layer3(
    const unsigned* __restrict__ hn8_in, unsigned* __restrict__ hp,
    const int* __restrict__ bcur, const unsigned* __restrict__ ebuf,
    const float* __restrict__ eps_arr, int layer,
    const _Float16* __restrict__ w1h, const float* __restrict__ b1,
    const float* __restrict__ g1, const float* __restrict__ bb1,
    const float* __restrict__ m1, const float* __restrict__ v1,
    const _Float16* __restrict__ w2h, const float* __restrict__ b2,
    const float* __restrict__ g2, const float* __restrict__ bb2,
    const float* __restrict__ m2, const float* __restrict__ v2) {
  __shared__ __align__(16) unsigned char zsb[64 * 128];
  __shared__ unsigned elds[BCAP];
  __shared__ int off[65];
  __shared__ int cur2[64];
  __shared__ float2 acs1[64], acs2[64];
  LAYER_PREAMBLE()
  BUCKET_SORT()
  GATHER()
  const int zrow = wave * 16 + rl;
  MLP()

  const int node = nbase + zrow;
  const bool val = node < NN;
#pragma unroll
  for (int m = 0; m < 4; m++) {
    v4f am = (m == 0) ? d0 : (m == 1) ? d1 : (m == 2) ? d2 : d3;
    float hv[4] = {0.f, 0.f, 0.f, 0.f};
    if (val) {
      uint2 hraw = *(const uint2*)(hp + (size_t)node * 32 + m * 8 + kl * 2);
      float2 ha = unpack_h2(hraw.x), hb = unpack_h2(hraw.y);
      hv[0] = ha.x;
      hv[1] = ha.y;
      hv[2] = hb.x;
      hv[3] = hb.y;
    }
    float vv[4];
#pragma unroll
    for (int r = 0; r < 4; r++) {
      int f = m * 16 + kl * 4 + r;
      float2 ac = acs2[f];
      float z2 = fmaxf(fmaf(am[r], ac.x, ac.y), 0.f);
      vv[r] = hv[r] + z2;
    }
    if (val) {
      uint2 st;
      st.x = pack_h2(vv[0], vv[1]);
      st.y = pack_h2(vv[2], vv[3]);
      *(uint2*)(hp + (size_t)node * 32 + m * 8 + kl * 2) = st;
    }
  }
}

// ---------- pooling (h in f16) ----------
__global__ __launch_bounds__(256) void k_pool(const unsigned* __restrict__ hp,
                                              const int* __restrict__ batch,
                                              float* __restrict__ sums) {
  const int lane = threadIdx.x & 63;
  const int gw = blockIdx.x * 4 + (threadIdx.x >> 6);
  const int base = gw * 64;
  if (base >= NN) return;
  const int end = min(base + 64, NN);
  float acc = 0.f;
  int cur = batch[base];
  for (int n = base; n < end; n++) {
    int g = batch[n];
    if (g != cur) {
      atomicAdd(&sums[cur * HD + lane], acc);
      acc = 0.f;
      cur = g;
    }
    unsigned u = hp[(size_t)n * 32 + (lane >> 1)];
    float2 f = unpack_h2(u);
    acc += (lane & 1) ? f.y : f.x;
  }
  atomicAdd(&sums[cur * HD + lane], acc);
}

__global__ __launch_bounds__(256) void k_div(const float* __restrict__ sums,
                                             const float* __restrict__ cnt,
                                             float* __restrict__ out) {
  int i = blockIdx.x * 256 + threadIdx.x;
  if (i < NG * HD) out[i] = sums[i] / fmaxf(cnt[i >> 6], 1.f);
}

// ---------- launch ----------
extern "C" void kernel_launch(void* const* d_in, const int* in_sizes, int n_in,
                              void* d_out, int out_size, void* d_ws,
                              size_t ws_size, hipStream_t stream) {
  const float* x = (const float*)d_in[0];
  const float* node_w = (const float*)d_in[1];
  const float* node_b = (const float*)d_in[2];
  const float* ln_g = (const float*)d_in[3];
  const float* ln_b = (const float*)d_in[4];
  const float* eps = (const float*)d_in[5];
  const float* w1 = (const float*)d_in[6];
  const float* b1 = (const float*)d_in[7];
  const float* bn1_g = (const float*)d_in[8];
  const float* bn1_b = (const float*)d_in[9];
  const float* bn1_m = (const float*)d_in[10];
  const float* bn1_v = (const float*)d_in[11];
  const float* w2 = (const float*)d_in[12];
  const float* b2 = (const float*)d_in[13];
  const float* bn2_g = (const float*)d_in[14];
  const float* bn2_b = (const float*)d_in[15];
  const float* bn2_m = (const float*)d_in[16];
  const float* bn2_v = (const float*)d_in[17];
  const int* edge_index = (const int*)d_in[18];
  const int* batch = (const int*)d_in[19];
  float* out = (float*)d_out;

  char* ws = (char*)d_ws;
  size_t off = 0;
  auto carve = [&](size_t bytes) {
    void* p = ws + off;
    off += (bytes + 255) & ~(size_t)255;
    return p;
  };
  unsigned* hp = (unsigned*)carve((size_t)NN * 32 * sizeof(unsigned));
  unsigned* hn8a = (unsigned*)carve((size_t)NN * 16 * sizeof(unsigned));
  unsigned* hn8b = (unsigned*)carve((size_t)NN * 16 * sizeof(unsigned));
  unsigned* ebuf = (unsigned*)carve((size_t)NBUCK * BCAP * sizeof(unsigned));
  unsigned* ebufA = (unsigned*)carve((size_t)NBIN * BINCAP * sizeof(unsigned));
  int* bcur = (int*)carve((size_t)NBUCK * 16 * sizeof(int));
  int* acur = (int*)carve((size_t)NBIN * 16 * sizeof(int));
  float* sums = (float*)carve((size_t)NG * HD * sizeof(float));
  float* cnt = (float*)carve((size_t)NG * sizeof(float));
  _Float16* wenc = (_Float16*)carve((size_t)HD * DIN * sizeof(_Float16));
  _Float16* w1h = (_Float16*)carve((size_t)NL * HD * HD * sizeof(_Float16));
  _Float16* w2h = (_Float16*)carve((size_t)NL * HD * HD * sizeof(_Float16));

  const int* e_src = edge_index;
  const int* e_dst = edge_index + NE;

  k_wconv<<<(NBUCK * 16 + 255) / 256, 256, 0, stream>>>(
      node_w, w1, w2, batch, wenc, w1h, w2h, bcur, acur, sums, cnt);
  k_binA<<<BINA_BLOCKS, 256, 0, stream>>>(e_src, e_dst, acur, ebufA);
  k_binB_enc<<<NBIN * SB + NBENC, 256, 0, stream>>>(acur, ebufA, bcur, ebuf,
                                                    x, wenc, node_b, ln_g,
                                                    ln_b, hp, hn8a);

  for (int l = 0; l < NL - 1; l++) {
    const unsigned* hin = (l & 1) ? hn8b : hn8a;
    unsigned* hout = (l & 1) ? hn8a : hn8b;
    k_layer<<<NBUCK, 256, 0, stream>>>(
        hin, hp, hout, bcur, ebuf, eps, l, w1h + (size_t)l * HD * HD,
        b1 + l * HD, bn1_g + l * HD, bn1_b + l * HD, bn1_m + l * HD,
        bn1_v + l * HD, w2h + (size_t)l * HD * HD, b2 + l * HD, bn2_g + l * HD,
        bn2_b + l * HD, bn2_m + l * HD, bn2_v + l * HD, ln_g + (l + 1) * HD,
        ln_b + (l + 1) * HD);
  }
  {
    const int l = NL - 1;
    const unsigned* hin = (l & 1) ? hn8b : hn8a;
    k_layer3<<<NBUCK, 256, 0, stream>>>(
        hin, hp, bcur, ebuf, eps, l, w1h + (size_t)l * HD * HD, b1 + l * HD,
        bn1_g + l * HD, bn1_b + l * HD, bn1_m + l * HD, bn1_v + l * HD,
        w2h + (size_t)l * HD * HD, b2 + l * HD, bn2_g + l * HD, bn2_b + l * HD,
        bn2_m + l * HD, bn2_v + l * HD);
  }

  k_pool<<<(NN + 255) / 256, 256, 0, stream>>>(hp, batch, sums);
  k_div<<<(NG * HD + 255) / 256, 256, 0, stream>>>(sums, cnt, out);
}